// Round 1
// baseline (236.995 us; speedup 1.0000x reference)
//
#include <hip/hip_runtime.h>
#include <hip/hip_bf16.h>

// Problem constants
#define NB 16        // batches
#define SS 2048      // S
#define FF 512       // F
// S*F = 2^20 per batch

typedef __bf16 bf16_t;
typedef __bf16 bf16x8 __attribute__((ext_vector_type(8)));
typedef __bf16 bf16x4 __attribute__((ext_vector_type(4)));
typedef float  f32x4  __attribute__((ext_vector_type(4)));

// ---------------------------------------------------------------- LN stats
__global__ __launch_bounds__(64) void zero_stats(float* sums) {
    if (threadIdx.x < 32) sums[threadIdx.x] = 0.0f;
}

__global__ __launch_bounds__(256) void stats_kernel(const float* __restrict__ x,
                                                    float* __restrict__ sums) {
    const int b = blockIdx.y;
    const float* xb = x + ((size_t)b << 20) + (size_t)blockIdx.x * 16384;
    float s = 0.0f, ss = 0.0f;
#pragma unroll
    for (int i = 0; i < 16; ++i) {
        const float4 v = *(const float4*)&xb[(threadIdx.x + i * 256) * 4];
        s  += v.x + v.y + v.z + v.w;
        ss += v.x * v.x + v.y * v.y + v.z * v.z + v.w * v.w;
    }
#pragma unroll
    for (int off = 32; off > 0; off >>= 1) {
        s  += __shfl_down(s, off);
        ss += __shfl_down(ss, off);
    }
    __shared__ float ps[4], pss[4];
    const int w = threadIdx.x >> 6, lane = threadIdx.x & 63;
    if (lane == 0) { ps[w] = s; pss[w] = ss; }
    __syncthreads();
    if (threadIdx.x == 0) {
        atomicAdd(&sums[b],      ps[0] + ps[1] + ps[2] + ps[3]);
        atomicAdd(&sums[16 + b], pss[0] + pss[1] + pss[2] + pss[3]);
    }
}

__global__ __launch_bounds__(64) void finalize_stats(const float* __restrict__ sums,
                                                     float* __restrict__ musig) {
    const int b = threadIdx.x;
    if (b < 16) {
        const float inv_n = 1.0f / 1048576.0f;
        const float mu  = sums[b] * inv_n;
        const float var = sums[16 + b] * inv_n - mu * mu;
        musig[b]      = mu;
        musig[16 + b] = rsqrtf(var + 1e-5f);
    }
}

// ------------------------------------------------- x_norm -> Y bf16 [b][f][s]
__global__ __launch_bounds__(256) void ynorm_kernel(const float* __restrict__ x,
                                                    const float* __restrict__ lw,
                                                    const float* __restrict__ lb,
                                                    const float* __restrict__ musig,
                                                    bf16_t* __restrict__ Y) {
    __shared__ bf16_t t[32][33];
    const int b = blockIdx.z;
    const int f0 = blockIdx.x * 32, s0 = blockIdx.y * 32;
    const float mu = musig[b], rs = musig[16 + b];
    const int c = threadIdx.x & 31, rb = threadIdx.x >> 5;   // rb in 0..7
#pragma unroll
    for (int i = 0; i < 4; ++i) {
        const int s_loc = rb + i * 8;
        const size_t idx = (size_t)(s0 + s_loc) * FF + f0 + c;
        const float yv = (x[((size_t)b << 20) + idx] - mu) * rs * lw[idx] + lb[idx];
        t[s_loc][c] = (bf16_t)yv;
    }
    __syncthreads();
#pragma unroll
    for (int i = 0; i < 4; ++i) {
        const int f_loc = rb + i * 8;
        Y[((size_t)b << 20) + (size_t)(f0 + f_loc) * SS + s0 + c] = t[c][f_loc];
    }
}

// ---------------------------------------------------------------- Wv -> bf16
__global__ __launch_bounds__(256) void cast_wv(const float* __restrict__ Wv,
                                               bf16_t* __restrict__ Wvb) {
    const size_t i = ((size_t)blockIdx.x * 256 + threadIdx.x) * 4;
    const float4 v = *(const float4*)&Wv[i];
    bf16x4 o;
    o[0] = (bf16_t)v.x; o[1] = (bf16_t)v.y; o[2] = (bf16_t)v.z; o[3] = (bf16_t)v.w;
    *(bf16x4*)&Wvb[i] = o;
}

// -------------------------------------------------- Q,K: [b*F] rows, R=4 each
__global__ __launch_bounds__(256) void qk_kernel(const bf16_t* __restrict__ Y,
                                                 const float* __restrict__ Wq,
                                                 const float* __restrict__ bq,
                                                 const float* __restrict__ Wk,
                                                 const float* __restrict__ bk,
                                                 float* __restrict__ Qo,
                                                 float* __restrict__ Ko) {
    const int w = threadIdx.x >> 6, lane = threadIdx.x & 63;
    const int row = blockIdx.x * 4 + w;              // b*512 + f
    const bf16_t* y = Y + (size_t)row * SS;
    float qa[4] = {0.f, 0.f, 0.f, 0.f}, ka[4] = {0.f, 0.f, 0.f, 0.f};
#pragma unroll
    for (int c = 0; c < 4; ++c) {
        const int s = c * 512 + lane * 8;
        const bf16x8 yv = *(const bf16x8*)&y[s];
        float yf[8];
#pragma unroll
        for (int j = 0; j < 8; ++j) yf[j] = (float)yv[j];
#pragma unroll
        for (int r = 0; r < 4; ++r) {
            const float4 a0 = *(const float4*)&Wq[r * SS + s];
            const float4 a1 = *(const float4*)&Wq[r * SS + s + 4];
            const float4 c0 = *(const float4*)&Wk[r * SS + s];
            const float4 c1 = *(const float4*)&Wk[r * SS + s + 4];
            qa[r] += yf[0]*a0.x + yf[1]*a0.y + yf[2]*a0.z + yf[3]*a0.w
                   + yf[4]*a1.x + yf[5]*a1.y + yf[6]*a1.z + yf[7]*a1.w;
            ka[r] += yf[0]*c0.x + yf[1]*c0.y + yf[2]*c0.z + yf[3]*c0.w
                   + yf[4]*c1.x + yf[5]*c1.y + yf[6]*c1.z + yf[7]*c1.w;
        }
    }
#pragma unroll
    for (int off = 32; off > 0; off >>= 1) {
#pragma unroll
        for (int r = 0; r < 4; ++r) {
            qa[r] += __shfl_down(qa[r], off);
            ka[r] += __shfl_down(ka[r], off);
        }
    }
    if (lane == 0) {
#pragma unroll
        for (int r = 0; r < 4; ++r) {
            Qo[(size_t)row * 4 + r] = qa[r] + bq[r];
            Ko[(size_t)row * 4 + r] = ka[r] + bk[r];
        }
    }
}

// ----------------------------------- A = softmax(Q K^T / sqrt(4)), bf16 output
__global__ __launch_bounds__(256) void softmax_kernel(const float* __restrict__ Qo,
                                                      const float* __restrict__ Ko,
                                                      bf16_t* __restrict__ Aout) {
    const int w = threadIdx.x >> 6, lane = threadIdx.x & 63;
    const int row = blockIdx.x * 4 + w;              // b*512 + f
    const int b = row >> 9;
    const float4 q = *(const float4*)&Qo[(size_t)row * 4];
    const float* kb = Ko + (size_t)b * FF * 4;
    float sc[8];
#pragma unroll
    for (int j = 0; j < 8; ++j) {
        const float4 kv = *(const float4*)&kb[(lane * 8 + j) * 4];
        sc[j] = (q.x*kv.x + q.y*kv.y + q.z*kv.z + q.w*kv.w) * 0.5f;
    }
    float mx = sc[0];
#pragma unroll
    for (int j = 1; j < 8; ++j) mx = fmaxf(mx, sc[j]);
#pragma unroll
    for (int off = 32; off > 0; off >>= 1) mx = fmaxf(mx, __shfl_xor(mx, off));
    float sum = 0.f;
#pragma unroll
    for (int j = 0; j < 8; ++j) { sc[j] = __expf(sc[j] - mx); sum += sc[j]; }
#pragma unroll
    for (int off = 32; off > 0; off >>= 1) sum += __shfl_xor(sum, off);
    const float inv = 1.0f / sum;
    bf16x8 o;
#pragma unroll
    for (int j = 0; j < 8; ++j) o[j] = (bf16_t)(sc[j] * inv);
    *(bf16x8*)&Aout[(size_t)row * FF + lane * 8] = o;
}

// --------------------------------------------------------------- NT bf16 GEMM
// C[M][N] = A[M][K] * B[N][K]^T  (both K-contiguous), batched, bf16 out.
// 128x128 tile, BK=64, 4 waves (2x2 of 64x64), m97 structure + chunk-XOR swizzle.
__global__ __launch_bounds__(256) void gemm_nt_bf16(
        const bf16_t* __restrict__ Abase, long long strideA, int lda,
        const bf16_t* __restrict__ Bbase, long long strideB, int ldb,
        bf16_t* __restrict__ Cbase, long long strideC, int ldc,
        int Kdim, const float* __restrict__ bias_m) {
    __shared__ bf16_t As[128 * 64];
    __shared__ bf16_t Bs[128 * 64];
    const int tid = threadIdx.x;
    const int w = tid >> 6, lane = tid & 63;
    const int m0 = blockIdx.x * 128, n0 = blockIdx.y * 128;
    const bf16_t* A = Abase + (size_t)blockIdx.z * (size_t)strideA;
    const bf16_t* B = Bbase + (size_t)blockIdx.z * (size_t)strideB;
    bf16_t* C = Cbase + (size_t)blockIdx.z * (size_t)strideC;

    const int wm = (w >> 1) * 64, wn = (w & 1) * 64;
    const int srow = lane >> 3, cslot = lane & 7;

    f32x4 acc[4][4] = {};

    for (int k0 = 0; k0 < Kdim; k0 += 64) {
        // Stage A tile: wave w loads rows [w*32, w*32+32). Linear LDS dest
        // (global_load_lds writes base + lane*16); chunk index XOR-swizzled on
        // the GLOBAL source so reads can de-conflict (rule: both-sides swizzle).
#pragma unroll
        for (int i = 0; i < 4; ++i) {
            const int r = w * 32 + i * 8 + srow;
            const int gc = cslot ^ (r & 7);
            const bf16_t* gp = A + (size_t)(m0 + r) * lda + (k0 + gc * 8);
            __builtin_amdgcn_global_load_lds(
                (const __attribute__((address_space(1))) unsigned int*)gp,
                (__attribute__((address_space(3))) unsigned int*)&As[(w * 32 + i * 8) * 64],
                16, 0, 0);
        }
#pragma unroll
        for (int i = 0; i < 4; ++i) {
            const int r = w * 32 + i * 8 + srow;
            const int gc = cslot ^ (r & 7);
            const bf16_t* gp = B + (size_t)(n0 + r) * ldb + (k0 + gc * 8);
            __builtin_amdgcn_global_load_lds(
                (const __attribute__((address_space(1))) unsigned int*)gp,
                (__attribute__((address_space(3))) unsigned int*)&Bs[(w * 32 + i * 8) * 64],
                16, 0, 0);
        }
        __syncthreads();   // compiler emits vmcnt(0) drain before s_barrier

#pragma unroll
        for (int ks = 0; ks < 2; ++ks) {
            const int kc = ks * 4 + (lane >> 4);
            bf16x8 af[4], bff[4];
#pragma unroll
            for (int mt = 0; mt < 4; ++mt) {
                const int row = wm + mt * 16 + (lane & 15);
                af[mt] = *(const bf16x8*)&As[row * 64 + ((kc ^ (row & 7)) << 3)];
            }
#pragma unroll
            for (int nt = 0; nt < 4; ++nt) {
                const int row = wn + nt * 16 + (lane & 15);
                bff[nt] = *(const bf16x8*)&Bs[row * 64 + ((kc ^ (row & 7)) << 3)];
            }
#pragma unroll
            for (int mt = 0; mt < 4; ++mt) {
#pragma unroll
                for (int nt = 0; nt < 4; ++nt) {
                    acc[mt][nt] = __builtin_amdgcn_mfma_f32_16x16x32_bf16(
                        af[mt], bff[nt], acc[mt][nt], 0, 0, 0);
                }
            }
        }
        __syncthreads();
    }

    // Epilogue: C/D layout row=(lane>>4)*4+reg, col=lane&15 (guide-verified)
#pragma unroll
    for (int mt = 0; mt < 4; ++mt) {
#pragma unroll
        for (int r = 0; r < 4; ++r) {
            const int row = m0 + wm + mt * 16 + (lane >> 4) * 4 + r;
            const float bm = bias_m ? bias_m[row] : 0.0f;
#pragma unroll
            for (int nt = 0; nt < 4; ++nt) {
                const int col = n0 + wn + nt * 16 + (lane & 15);
                C[(size_t)row * ldc + col] = (bf16_t)(acc[mt][nt][r] + bm);
            }
        }
    }
}

// -------------------------------------------------------------- final epilogue
// out[b][s][f] = x_norm(exact fp32) + alpha*Ot[b][s][f] + (1+beta)*Vt[b][s][f]
__global__ __launch_bounds__(256) void epilogue_kernel(const float* __restrict__ x,
                                                       const float* __restrict__ lw,
                                                       const float* __restrict__ lb,
                                                       const bf16_t* __restrict__ Ot,
                                                       const bf16_t* __restrict__ Vt,
                                                       const float* __restrict__ musig,
                                                       const float* __restrict__ alphap,
                                                       const float* __restrict__ betap,
                                                       float* __restrict__ out) {
    const size_t i4 = ((size_t)blockIdx.x * 256 + threadIdx.x) * 4;
    const size_t b = i4 >> 20;
    const size_t rr = i4 & 1048575;
    const float mu = musig[b], rs = musig[16 + b];
    const float alpha = alphap[0];
    const float onepb = 1.0f + betap[0];
    const float4 xv  = *(const float4*)&x[i4];
    const float4 wv  = *(const float4*)&lw[rr];
    const float4 bbv = *(const float4*)&lb[rr];
    const bf16x4 ov = *(const bf16x4*)&Ot[i4];
    const bf16x4 vv = *(const bf16x4*)&Vt[i4];
    float4 o;
    o.x = (xv.x - mu) * rs * wv.x + bbv.x + alpha * (float)ov[0] + onepb * (float)vv[0];
    o.y = (xv.y - mu) * rs * wv.y + bbv.y + alpha * (float)ov[1] + onepb * (float)vv[1];
    o.z = (xv.z - mu) * rs * wv.z + bbv.z + alpha * (float)ov[2] + onepb * (float)vv[2];
    o.w = (xv.w - mu) * rs * wv.w + bbv.w + alpha * (float)ov[3] + onepb * (float)vv[3];
    *(float4*)&out[i4] = o;
}

extern "C" void kernel_launch(void* const* d_in, const int* in_sizes, int n_in,
                              void* d_out, int out_size, void* d_ws, size_t ws_size,
                              hipStream_t stream) {
    const float* x   = (const float*)d_in[0];
    const float* Wq  = (const float*)d_in[1];
    const float* bq  = (const float*)d_in[2];
    const float* Wk  = (const float*)d_in[3];
    const float* bk  = (const float*)d_in[4];
    const float* Wv  = (const float*)d_in[5];
    const float* bv  = (const float*)d_in[6];
    const float* lw  = (const float*)d_in[7];
    const float* lb  = (const float*)d_in[8];
    const float* alp = (const float*)d_in[9];
    const float* bet = (const float*)d_in[10];
    float* out = (float*)d_out;

    char* ws = (char*)d_ws;
    float*  sums  = (float*)(ws + 0);           // 32 f32: sum[16], sumsq[16]
    float*  musig = (float*)(ws + 128);         // 32 f32: mu[16], rsig[16]
    float*  Qo    = (float*)(ws + 256);         // 16*512*4 f32 = 128 KiB
    float*  Ko    = (float*)(ws + 256 + 131072);
    bf16_t* Wvb   = (bf16_t*)(ws + 262400);     // 2048*2048 bf16 = 8 MiB
    bf16_t* Asm   = (bf16_t*)(ws + 8651008);    // 16*512*512 bf16 = 8 MiB
    bf16_t* Vt    = (bf16_t*)(ws + 17039616);   // 16*2048*512 bf16 = 32 MiB
    bf16_t* Y     = (bf16_t*)(ws + 50594048);   // 16*512*2048 bf16 = 32 MiB
    bf16_t* Ot    = Y;  // alias: Y is dead after gemm1 (gemm2 reads Vt+Asm only)

    zero_stats<<<1, 64, 0, stream>>>(sums);
    stats_kernel<<<dim3(64, 16), 256, 0, stream>>>(x, sums);
    finalize_stats<<<1, 64, 0, stream>>>(sums, musig);
    cast_wv<<<4096, 256, 0, stream>>>(Wv, Wvb);
    ynorm_kernel<<<dim3(16, 64, 16), 256, 0, stream>>>(x, lw, lb, musig, Y);
    qk_kernel<<<2048, 256, 0, stream>>>(Y, Wq, bq, Wk, bk, Qo, Ko);
    softmax_kernel<<<2048, 256, 0, stream>>>(Qo, Ko, Asm);
    // Vt[b,t,f] = sum_s Wv[t,s]*Y[b,f,s] + bv[t]   (M=2048,N=512,K=2048)
    gemm_nt_bf16<<<dim3(16, 4, 16), 256, 0, stream>>>(
        Wvb, 0, SS, Y, 1 << 20, SS, Vt, 1 << 20, FF, SS, bv);
    // Ot[b,t,f] = sum_g Vt[b,t,g]*Asm[b,f,g]       (M=2048,N=512,K=512)
    gemm_nt_bf16<<<dim3(16, 4, 16), 256, 0, stream>>>(
        Vt, 1 << 20, FF, Asm, FF * FF, FF, Ot, 1 << 20, FF, FF, nullptr);
    epilogue_kernel<<<16384, 256, 0, stream>>>(x, lw, lb, Ot, Vt, musig, alp, bet, out);
}

// Round 2
// 234.500 us; speedup vs baseline: 1.0106x; 1.0106x over previous
//
#include <hip/hip_runtime.h>
#include <hip/hip_bf16.h>

// Problem constants
#define NB 16        // batches
#define SS 2048      // S
#define FF 512       // F
// S*F = 2^20 per batch

typedef __bf16 bf16_t;
typedef __bf16 bf16x8 __attribute__((ext_vector_type(8)));
typedef __bf16 bf16x4 __attribute__((ext_vector_type(4)));
typedef float  f32x4  __attribute__((ext_vector_type(4)));

// ---------------------------------------------------------------- LN stats
__global__ __launch_bounds__(64) void zero_stats(float* sums) {
    if (threadIdx.x < 32) sums[threadIdx.x] = 0.0f;
}

__global__ __launch_bounds__(256) void stats_kernel(const float* __restrict__ x,
                                                    float* __restrict__ sums) {
    const int b = blockIdx.y;
    const float* xb = x + ((size_t)b << 20) + (size_t)blockIdx.x * 16384;
    float s = 0.0f, ss = 0.0f;
#pragma unroll
    for (int i = 0; i < 16; ++i) {
        const float4 v = *(const float4*)&xb[(threadIdx.x + i * 256) * 4];
        s  += v.x + v.y + v.z + v.w;
        ss += v.x * v.x + v.y * v.y + v.z * v.z + v.w * v.w;
    }
#pragma unroll
    for (int off = 32; off > 0; off >>= 1) {
        s  += __shfl_down(s, off);
        ss += __shfl_down(ss, off);
    }
    __shared__ float ps[4], pss[4];
    const int w = threadIdx.x >> 6, lane = threadIdx.x & 63;
    if (lane == 0) { ps[w] = s; pss[w] = ss; }
    __syncthreads();
    if (threadIdx.x == 0) {
        atomicAdd(&sums[b],      ps[0] + ps[1] + ps[2] + ps[3]);
        atomicAdd(&sums[16 + b], pss[0] + pss[1] + pss[2] + pss[3]);
    }
}

__global__ __launch_bounds__(64) void finalize_stats(const float* __restrict__ sums,
                                                     float* __restrict__ musig) {
    const int b = threadIdx.x;
    if (b < 16) {
        const float inv_n = 1.0f / 1048576.0f;
        const float mu  = sums[b] * inv_n;
        const float var = sums[16 + b] * inv_n - mu * mu;
        musig[b]      = mu;
        musig[16 + b] = rsqrtf(var + 1e-5f);
    }
}

// ------------------------------------------------- x_norm -> Y bf16 [b][f][s]
__global__ __launch_bounds__(256) void ynorm_kernel(const float* __restrict__ x,
                                                    const float* __restrict__ lw,
                                                    const float* __restrict__ lb,
                                                    const float* __restrict__ musig,
                                                    bf16_t* __restrict__ Y) {
    __shared__ bf16_t t[32][33];
    const int b = blockIdx.z;
    const int f0 = blockIdx.x * 32, s0 = blockIdx.y * 32;
    const float mu = musig[b], rs = musig[16 + b];
    const int c = threadIdx.x & 31, rb = threadIdx.x >> 5;   // rb in 0..7
#pragma unroll
    for (int i = 0; i < 4; ++i) {
        const int s_loc = rb + i * 8;
        const size_t idx = (size_t)(s0 + s_loc) * FF + f0 + c;
        const float yv = (x[((size_t)b << 20) + idx] - mu) * rs * lw[idx] + lb[idx];
        t[s_loc][c] = (bf16_t)yv;
    }
    __syncthreads();
#pragma unroll
    for (int i = 0; i < 4; ++i) {
        const int f_loc = rb + i * 8;
        Y[((size_t)b << 20) + (size_t)(f0 + f_loc) * SS + s0 + c] = t[c][f_loc];
    }
}

// ---------------------------------------------------------------- Wv -> bf16
__global__ __launch_bounds__(256) void cast_wv(const float* __restrict__ Wv,
                                               bf16_t* __restrict__ Wvb) {
    const size_t i = ((size_t)blockIdx.x * 256 + threadIdx.x) * 4;
    const float4 v = *(const float4*)&Wv[i];
    bf16x4 o;
    o[0] = (bf16_t)v.x; o[1] = (bf16_t)v.y; o[2] = (bf16_t)v.z; o[3] = (bf16_t)v.w;
    *(bf16x4*)&Wvb[i] = o;
}

// -------------------------------------------------- Q,K: [b*F] rows, R=4 each
__global__ __launch_bounds__(256) void qk_kernel(const bf16_t* __restrict__ Y,
                                                 const float* __restrict__ Wq,
                                                 const float* __restrict__ bq,
                                                 const float* __restrict__ Wk,
                                                 const float* __restrict__ bk,
                                                 float* __restrict__ Qo,
                                                 float* __restrict__ Ko) {
    const int w = threadIdx.x >> 6, lane = threadIdx.x & 63;
    const int row = blockIdx.x * 4 + w;              // b*512 + f
    const bf16_t* y = Y + (size_t)row * SS;
    float qa[4] = {0.f, 0.f, 0.f, 0.f}, ka[4] = {0.f, 0.f, 0.f, 0.f};
#pragma unroll
    for (int c = 0; c < 4; ++c) {
        const int s = c * 512 + lane * 8;
        const bf16x8 yv = *(const bf16x8*)&y[s];
        float yf[8];
#pragma unroll
        for (int j = 0; j < 8; ++j) yf[j] = (float)yv[j];
#pragma unroll
        for (int r = 0; r < 4; ++r) {
            const float4 a0 = *(const float4*)&Wq[r * SS + s];
            const float4 a1 = *(const float4*)&Wq[r * SS + s + 4];
            const float4 c0 = *(const float4*)&Wk[r * SS + s];
            const float4 c1 = *(const float4*)&Wk[r * SS + s + 4];
            qa[r] += yf[0]*a0.x + yf[1]*a0.y + yf[2]*a0.z + yf[3]*a0.w
                   + yf[4]*a1.x + yf[5]*a1.y + yf[6]*a1.z + yf[7]*a1.w;
            ka[r] += yf[0]*c0.x + yf[1]*c0.y + yf[2]*c0.z + yf[3]*c0.w
                   + yf[4]*c1.x + yf[5]*c1.y + yf[6]*c1.z + yf[7]*c1.w;
        }
    }
#pragma unroll
    for (int off = 32; off > 0; off >>= 1) {
#pragma unroll
        for (int r = 0; r < 4; ++r) {
            qa[r] += __shfl_down(qa[r], off);
            ka[r] += __shfl_down(ka[r], off);
        }
    }
    if (lane == 0) {
#pragma unroll
        for (int r = 0; r < 4; ++r) {
            Qo[(size_t)row * 4 + r] = qa[r] + bq[r];
            Ko[(size_t)row * 4 + r] = ka[r] + bk[r];
        }
    }
}

// ----------------------------------- A = softmax(Q K^T / sqrt(4)), bf16 output
__global__ __launch_bounds__(256) void softmax_kernel(const float* __restrict__ Qo,
                                                      const float* __restrict__ Ko,
                                                      bf16_t* __restrict__ Aout) {
    const int w = threadIdx.x >> 6, lane = threadIdx.x & 63;
    const int row = blockIdx.x * 4 + w;              // b*512 + f
    const int b = row >> 9;
    const float4 q = *(const float4*)&Qo[(size_t)row * 4];
    const float* kb = Ko + (size_t)b * FF * 4;
    float sc[8];
#pragma unroll
    for (int j = 0; j < 8; ++j) {
        const float4 kv = *(const float4*)&kb[(lane * 8 + j) * 4];
        sc[j] = (q.x*kv.x + q.y*kv.y + q.z*kv.z + q.w*kv.w) * 0.5f;
    }
    float mx = sc[0];
#pragma unroll
    for (int j = 1; j < 8; ++j) mx = fmaxf(mx, sc[j]);
#pragma unroll
    for (int off = 32; off > 0; off >>= 1) mx = fmaxf(mx, __shfl_xor(mx, off));
    float sum = 0.f;
#pragma unroll
    for (int j = 0; j < 8; ++j) { sc[j] = __expf(sc[j] - mx); sum += sc[j]; }
#pragma unroll
    for (int off = 32; off > 0; off >>= 1) sum += __shfl_xor(sum, off);
    const float inv = 1.0f / sum;
    bf16x8 o;
#pragma unroll
    for (int j = 0; j < 8; ++j) o[j] = (bf16_t)(sc[j] * inv);
    *(bf16x8*)&Aout[(size_t)row * FF + lane * 8] = o;
}

// --------------------------------------------------------------- NT bf16 GEMM
// C[M][N] = A[M][K] * B[N][K]^T, batched, bf16 out. 256x256 tile, BK=32,
// 8 waves (2M x 4N, each wave owns 128x64), triple-buffered LDS pipeline with
// prefetch distance 2 and counted vmcnt(4) at tile boundaries (T3+T4), raw
// s_barrier (no drain), chunk-XOR swizzle (both-sides), setprio around MFMA.
__global__ __launch_bounds__(512, 2) void gemm_nt_pipe(
        const bf16_t* __restrict__ Abase, long long strideA, int lda,
        const bf16_t* __restrict__ Bbase, long long strideB, int ldb,
        bf16_t* __restrict__ Cbase, long long strideC, int ldc,
        int NT, const float* __restrict__ bias_m) {
    __shared__ bf16_t As[3][256 * 32];   // 3 x 16 KiB
    __shared__ bf16_t Bs[3][256 * 32];   // 3 x 16 KiB  (total 96 KiB)
    const int tid = threadIdx.x;
    const int w = tid >> 6, lane = tid & 63;
    const int m0 = blockIdx.x * 256, n0 = blockIdx.y * 256;
    const bf16_t* A = Abase + (size_t)blockIdx.z * (size_t)strideA;
    const bf16_t* B = Bbase + (size_t)blockIdx.z * (size_t)strideB;
    bf16_t* C = Cbase + (size_t)blockIdx.z * (size_t)strideC;

    const int wm = w >> 2, wn = w & 3;   // wave tile: rows wm*128.., cols wn*64..

    // ---- staging precompute (2 steps A + 2 steps B per K-tile, 1KB/wave/step)
    // step s covers rows s*128..s*128+127; wave w covers 16 rows within it.
    const int srow0 = w * 16 + (lane >> 2);
    const int srow1 = 128 + srow0;
    const int sc0 = (lane & 3) ^ ((srow0 >> 1) & 3);  // inverse-swizzled source chunk
    const int sc1 = (lane & 3) ^ ((srow1 >> 1) & 3);
    const bf16_t* gA0 = A + (size_t)(m0 + srow0) * lda + sc0 * 8;
    const bf16_t* gA1 = A + (size_t)(m0 + srow1) * lda + sc1 * 8;
    const bf16_t* gB0 = B + (size_t)(n0 + srow0) * ldb + sc0 * 8;
    const bf16_t* gB1 = B + (size_t)(n0 + srow1) * ldb + sc1 * 8;
    const int ldsoff0 = (w * 16) * 32;        // wave-uniform LDS elem offsets
    const int ldsoff1 = (128 + w * 16) * 32;

#define STAGE(bi, kt) do {                                                         \
    const int koff_ = (kt) * 32;                                                   \
    __builtin_amdgcn_global_load_lds(                                              \
        (const __attribute__((address_space(1))) unsigned int*)(gA0 + koff_),      \
        (__attribute__((address_space(3))) unsigned int*)&As[bi][ldsoff0], 16, 0, 0); \
    __builtin_amdgcn_global_load_lds(                                              \
        (const __attribute__((address_space(1))) unsigned int*)(gA1 + koff_),      \
        (__attribute__((address_space(3))) unsigned int*)&As[bi][ldsoff1], 16, 0, 0); \
    __builtin_amdgcn_global_load_lds(                                              \
        (const __attribute__((address_space(1))) unsigned int*)(gB0 + koff_),      \
        (__attribute__((address_space(3))) unsigned int*)&Bs[bi][ldsoff0], 16, 0, 0); \
    __builtin_amdgcn_global_load_lds(                                              \
        (const __attribute__((address_space(1))) unsigned int*)(gB1 + koff_),      \
        (__attribute__((address_space(3))) unsigned int*)&Bs[bi][ldsoff1], 16, 0, 0); \
} while (0)

    // ---- fragment-read offsets (swizzled on the read side, same XOR)
    const int kc = lane >> 4;                 // k-chunk 0..3 (8 bf16 each)
    int offA[8], offB[4];
#pragma unroll
    for (int mt = 0; mt < 8; ++mt) {
        const int r = wm * 128 + mt * 16 + (lane & 15);
        offA[mt] = r * 32 + ((kc ^ ((r >> 1) & 3)) << 3);
    }
#pragma unroll
    for (int nt = 0; nt < 4; ++nt) {
        const int r = wn * 64 + nt * 16 + (lane & 15);
        offB[nt] = r * 32 + ((kc ^ ((r >> 1) & 3)) << 3);
    }

    f32x4 acc[8][4] = {};

    const int mask = NT - 1;                  // NT is a power of two (64 or 16)
    STAGE(0, 0);
    STAGE(1, 1);
    asm volatile("s_waitcnt vmcnt(4)\n\ts_barrier" ::: "memory");  // tile0 landed

    int cur = 0;
    for (int t = 0; t < NT; ++t) {
        const int sb = (cur == 0) ? 2 : cur - 1;      // buffer for tile t+2
        STAGE(sb, (t + 2) & mask);                     // dummy re-stage at the tail
        const bf16_t* as = As[cur];
        const bf16_t* bs = Bs[cur];
        bf16x8 af[8], bfr[4];
        // phase A: lower half of M frags
#pragma unroll
        for (int mt = 0; mt < 4; ++mt) af[mt] = *(const bf16x8*)&as[offA[mt]];
#pragma unroll
        for (int nt = 0; nt < 4; ++nt) bfr[nt] = *(const bf16x8*)&bs[offB[nt]];
        asm volatile("s_waitcnt lgkmcnt(0)" ::: "memory");
        __builtin_amdgcn_sched_barrier(0);
        __builtin_amdgcn_s_setprio(1);
#pragma unroll
        for (int mt = 0; mt < 4; ++mt)
#pragma unroll
            for (int nt = 0; nt < 4; ++nt)
                acc[mt][nt] = __builtin_amdgcn_mfma_f32_16x16x32_bf16(
                    af[mt], bfr[nt], acc[mt][nt], 0, 0, 0);
        __builtin_amdgcn_s_setprio(0);
        // phase B: upper half of M frags
#pragma unroll
        for (int mt = 4; mt < 8; ++mt) af[mt] = *(const bf16x8*)&as[offA[mt]];
        asm volatile("s_waitcnt lgkmcnt(0)" ::: "memory");
        __builtin_amdgcn_sched_barrier(0);
        __builtin_amdgcn_s_setprio(1);
#pragma unroll
        for (int mt = 4; mt < 8; ++mt)
#pragma unroll
            for (int nt = 0; nt < 4; ++nt)
                acc[mt][nt] = __builtin_amdgcn_mfma_f32_16x16x32_bf16(
                    af[mt], bfr[nt], acc[mt][nt], 0, 0, 0);
        __builtin_amdgcn_s_setprio(0);
        // counted boundary: tile t+1 forced landed (per-wave), t+2 stays in flight
        asm volatile("s_waitcnt vmcnt(4)\n\ts_barrier" ::: "memory");
        cur = (cur == 2) ? 0 : cur + 1;
    }
#undef STAGE

    // Epilogue: C/D layout row=(lane>>4)*4+reg, col=lane&15 (verified)
#pragma unroll
    for (int mt = 0; mt < 8; ++mt) {
#pragma unroll
        for (int r = 0; r < 4; ++r) {
            const int row = m0 + wm * 128 + mt * 16 + ((lane >> 4) << 2) + r;
            const float bm = bias_m ? bias_m[row] : 0.0f;
#pragma unroll
            for (int nt = 0; nt < 4; ++nt) {
                const int col = n0 + wn * 64 + nt * 16 + (lane & 15);
                C[(size_t)row * ldc + col] = (bf16_t)(acc[mt][nt][r] + bm);
            }
        }
    }
}

// -------------------------------------------------------------- final epilogue
// out[b][s][f] = x_norm(exact fp32) + alpha*Ot[b][s][f] + (1+beta)*Vt[b][s][f]
__global__ __launch_bounds__(256) void epilogue_kernel(const float* __restrict__ x,
                                                       const float* __restrict__ lw,
                                                       const float* __restrict__ lb,
                                                       const bf16_t* __restrict__ Ot,
                                                       const bf16_t* __restrict__ Vt,
                                                       const float* __restrict__ musig,
                                                       const float* __restrict__ alphap,
                                                       const float* __restrict__ betap,
                                                       float* __restrict__ out) {
    const size_t i4 = ((size_t)blockIdx.x * 256 + threadIdx.x) * 4;
    const size_t b = i4 >> 20;
    const size_t rr = i4 & 1048575;
    const float mu = musig[b], rs = musig[16 + b];
    const float alpha = alphap[0];
    const float onepb = 1.0f + betap[0];
    const float4 xv  = *(const float4*)&x[i4];
    const float4 wv  = *(const float4*)&lw[rr];
    const float4 bbv = *(const float4*)&lb[rr];
    const bf16x4 ov = *(const bf16x4*)&Ot[i4];
    const bf16x4 vv = *(const bf16x4*)&Vt[i4];
    float4 o;
    o.x = (xv.x - mu) * rs * wv.x + bbv.x + alpha * (float)ov[0] + onepb * (float)vv[0];
    o.y = (xv.y - mu) * rs * wv.y + bbv.y + alpha * (float)ov[1] + onepb * (float)vv[1];
    o.z = (xv.z - mu) * rs * wv.z + bbv.z + alpha * (float)ov[2] + onepb * (float)vv[2];
    o.w = (xv.w - mu) * rs * wv.w + bbv.w + alpha * (float)ov[3] + onepb * (float)vv[3];
    *(float4*)&out[i4] = o;
}

extern "C" void kernel_launch(void* const* d_in, const int* in_sizes, int n_in,
                              void* d_out, int out_size, void* d_ws, size_t ws_size,
                              hipStream_t stream) {
    const float* x   = (const float*)d_in[0];
    const float* Wq  = (const float*)d_in[1];
    const float* bq  = (const float*)d_in[2];
    const float* Wk  = (const float*)d_in[3];
    const float* bk  = (const float*)d_in[4];
    const float* Wv  = (const float*)d_in[5];
    const float* bv  = (const float*)d_in[6];
    const float* lw  = (const float*)d_in[7];
    const float* lb  = (const float*)d_in[8];
    const float* alp = (const float*)d_in[9];
    const float* bet = (const float*)d_in[10];
    float* out = (float*)d_out;

    char* ws = (char*)d_ws;
    float*  sums  = (float*)(ws + 0);           // 32 f32: sum[16], sumsq[16]
    float*  musig = (float*)(ws + 128);         // 32 f32: mu[16], rsig[16]
    float*  Qo    = (float*)(ws + 256);         // 16*512*4 f32 = 128 KiB
    float*  Ko    = (float*)(ws + 256 + 131072);
    bf16_t* Wvb   = (bf16_t*)(ws + 262400);     // 2048*2048 bf16 = 8 MiB
    bf16_t* Asm   = (bf16_t*)(ws + 8651008);    // 16*512*512 bf16 = 8 MiB
    bf16_t* Vt    = (bf16_t*)(ws + 17039616);   // 16*2048*512 bf16 = 32 MiB
    bf16_t* Y     = (bf16_t*)(ws + 50594048);   // 16*512*2048 bf16 = 32 MiB
    bf16_t* Ot    = Y;  // alias: Y is dead after gemm1 (gemm2 reads Vt+Asm only)

    zero_stats<<<1, 64, 0, stream>>>(sums);
    stats_kernel<<<dim3(64, 16), 256, 0, stream>>>(x, sums);
    finalize_stats<<<1, 64, 0, stream>>>(sums, musig);
    cast_wv<<<4096, 256, 0, stream>>>(Wv, Wvb);
    ynorm_kernel<<<dim3(16, 64, 16), 256, 0, stream>>>(x, lw, lb, musig, Y);
    qk_kernel<<<2048, 256, 0, stream>>>(Y, Wq, bq, Wk, bk, Qo, Ko);
    softmax_kernel<<<2048, 256, 0, stream>>>(Qo, Ko, Asm);
    // Vt[b,t,f] = sum_s Wv[t,s]*Y[b,f,s] + bv[t]   (M=2048,N=512,K=2048, NT=64)
    gemm_nt_pipe<<<dim3(8, 2, 16), 512, 0, stream>>>(
        Wvb, 0, SS, Y, 1 << 20, SS, Vt, 1 << 20, FF, 64, bv);
    // Ot[b,t,f] = sum_g Vt[b,t,g]*Asm[b,f,g]       (M=2048,N=512,K=512, NT=16)
    gemm_nt_pipe<<<dim3(8, 2, 16), 512, 0, stream>>>(
        Vt, 1 << 20, FF, Asm, FF * FF, FF, Ot, 1 << 20, FF, 16, nullptr);
    epilogue_kernel<<<16384, 256, 0, stream>>>(x, lw, lb, Ot, Vt, musig, alp, bet, out);
}

// Round 3
// 221.831 us; speedup vs baseline: 1.0684x; 1.0571x over previous
//
#include <hip/hip_runtime.h>
#include <hip/hip_bf16.h>

// Problem constants
#define NB 16        // batches
#define SS 2048      // S
#define FF 512       // F

typedef __bf16 bf16_t;
typedef __bf16 bf16x8 __attribute__((ext_vector_type(8)));
typedef __bf16 bf16x4 __attribute__((ext_vector_type(4)));
typedef float  f32x4  __attribute__((ext_vector_type(4)));

// ---------------------------------------------------------------- LN stats
__global__ __launch_bounds__(64) void zero_stats(float* sums) {
    if (threadIdx.x < 32) sums[threadIdx.x] = 0.0f;
}

__global__ __launch_bounds__(256) void stats_kernel(const float* __restrict__ x,
                                                    float* __restrict__ sums) {
    const int b = blockIdx.y;
    const float* xb = x + ((size_t)b << 20) + (size_t)blockIdx.x * 16384;
    float s = 0.0f, ss = 0.0f;
#pragma unroll
    for (int i = 0; i < 16; ++i) {
        const float4 v = *(const float4*)&xb[(threadIdx.x + i * 256) * 4];
        s  += v.x + v.y + v.z + v.w;
        ss += v.x * v.x + v.y * v.y + v.z * v.z + v.w * v.w;
    }
#pragma unroll
    for (int off = 32; off > 0; off >>= 1) {
        s  += __shfl_down(s, off);
        ss += __shfl_down(ss, off);
    }
    __shared__ float ps[4], pss[4];
    const int w = threadIdx.x >> 6, lane = threadIdx.x & 63;
    if (lane == 0) { ps[w] = s; pss[w] = ss; }
    __syncthreads();
    if (threadIdx.x == 0) {
        atomicAdd(&sums[b],      ps[0] + ps[1] + ps[2] + ps[3]);
        atomicAdd(&sums[16 + b], pss[0] + pss[1] + pss[2] + pss[3]);
    }
}

__global__ __launch_bounds__(64) void finalize_stats(const float* __restrict__ sums,
                                                     float* __restrict__ musig) {
    const int b = threadIdx.x;
    if (b < 16) {
        const float inv_n = 1.0f / 1048576.0f;
        const float mu  = sums[b] * inv_n;
        const float var = sums[16 + b] * inv_n - mu * mu;
        musig[b]      = mu;
        musig[16 + b] = rsqrtf(var + 1e-5f);
    }
}

// ------------------------------------------------- x_norm -> Y bf16 [b][f][s]
__global__ __launch_bounds__(256) void ynorm_kernel(const float* __restrict__ x,
                                                    const float* __restrict__ lw,
                                                    const float* __restrict__ lb,
                                                    const float* __restrict__ musig,
                                                    bf16_t* __restrict__ Y) {
    __shared__ bf16_t t[32][33];
    const int b = blockIdx.z;
    const int f0 = blockIdx.x * 32, s0 = blockIdx.y * 32;
    const float mu = musig[b], rs = musig[16 + b];
    const int c = threadIdx.x & 31, rb = threadIdx.x >> 5;   // rb in 0..7
#pragma unroll
    for (int i = 0; i < 4; ++i) {
        const int s_loc = rb + i * 8;
        const size_t idx = (size_t)(s0 + s_loc) * FF + f0 + c;
        const float yv = (x[((size_t)b << 20) + idx] - mu) * rs * lw[idx] + lb[idx];
        t[s_loc][c] = (bf16_t)yv;
    }
    __syncthreads();
#pragma unroll
    for (int i = 0; i < 4; ++i) {
        const int f_loc = rb + i * 8;
        Y[((size_t)b << 20) + (size_t)(f0 + f_loc) * SS + s0 + c] = t[c][f_loc];
    }
}

// ---------------------------------------------------------------- Wv -> bf16
__global__ __launch_bounds__(256) void cast_wv(const float* __restrict__ Wv,
                                               bf16_t* __restrict__ Wvb) {
    const size_t i = ((size_t)blockIdx.x * 256 + threadIdx.x) * 4;
    const float4 v = *(const float4*)&Wv[i];
    bf16x4 o;
    o[0] = (bf16_t)v.x; o[1] = (bf16_t)v.y; o[2] = (bf16_t)v.z; o[3] = (bf16_t)v.w;
    *(bf16x4*)&Wvb[i] = o;
}

// -------------------------------------------------- Q,K: [b*F] rows, R=4 each
__global__ __launch_bounds__(256) void qk_kernel(const bf16_t* __restrict__ Y,
                                                 const float* __restrict__ Wq,
                                                 const float* __restrict__ bq,
                                                 const float* __restrict__ Wk,
                                                 const float* __restrict__ bk,
                                                 float* __restrict__ Qo,
                                                 float* __restrict__ Ko) {
    const int w = threadIdx.x >> 6, lane = threadIdx.x & 63;
    const int row = blockIdx.x * 4 + w;              // b*512 + f
    const bf16_t* y = Y + (size_t)row * SS;
    float qa[4] = {0.f, 0.f, 0.f, 0.f}, ka[4] = {0.f, 0.f, 0.f, 0.f};
#pragma unroll
    for (int c = 0; c < 4; ++c) {
        const int s = c * 512 + lane * 8;
        const bf16x8 yv = *(const bf16x8*)&y[s];
        float yf[8];
#pragma unroll
        for (int j = 0; j < 8; ++j) yf[j] = (float)yv[j];
#pragma unroll
        for (int r = 0; r < 4; ++r) {
            const float4 a0 = *(const float4*)&Wq[r * SS + s];
            const float4 a1 = *(const float4*)&Wq[r * SS + s + 4];
            const float4 c0 = *(const float4*)&Wk[r * SS + s];
            const float4 c1 = *(const float4*)&Wk[r * SS + s + 4];
            qa[r] += yf[0]*a0.x + yf[1]*a0.y + yf[2]*a0.z + yf[3]*a0.w
                   + yf[4]*a1.x + yf[5]*a1.y + yf[6]*a1.z + yf[7]*a1.w;
            ka[r] += yf[0]*c0.x + yf[1]*c0.y + yf[2]*c0.z + yf[3]*c0.w
                   + yf[4]*c1.x + yf[5]*c1.y + yf[6]*c1.z + yf[7]*c1.w;
        }
    }
#pragma unroll
    for (int off = 32; off > 0; off >>= 1) {
#pragma unroll
        for (int r = 0; r < 4; ++r) {
            qa[r] += __shfl_down(qa[r], off);
            ka[r] += __shfl_down(ka[r], off);
        }
    }
    if (lane == 0) {
#pragma unroll
        for (int r = 0; r < 4; ++r) {
            Qo[(size_t)row * 4 + r] = qa[r] + bq[r];
            Ko[(size_t)row * 4 + r] = ka[r] + bk[r];
        }
    }
}

// ----------------------------------- A = softmax(Q K^T / sqrt(4)), bf16 output
__global__ __launch_bounds__(256) void softmax_kernel(const float* __restrict__ Qo,
                                                      const float* __restrict__ Ko,
                                                      bf16_t* __restrict__ Aout) {
    const int w = threadIdx.x >> 6, lane = threadIdx.x & 63;
    const int row = blockIdx.x * 4 + w;              // b*512 + f
    const int b = row >> 9;
    const float4 q = *(const float4*)&Qo[(size_t)row * 4];
    const float* kb = Ko + (size_t)b * FF * 4;
    float sc[8];
#pragma unroll
    for (int j = 0; j < 8; ++j) {
        const float4 kv = *(const float4*)&kb[(lane * 8 + j) * 4];
        sc[j] = (q.x*kv.x + q.y*kv.y + q.z*kv.z + q.w*kv.w) * 0.5f;
    }
    float mx = sc[0];
#pragma unroll
    for (int j = 1; j < 8; ++j) mx = fmaxf(mx, sc[j]);
#pragma unroll
    for (int off = 32; off > 0; off >>= 1) mx = fmaxf(mx, __shfl_xor(mx, off));
    float sum = 0.f;
#pragma unroll
    for (int j = 0; j < 8; ++j) { sc[j] = __expf(sc[j] - mx); sum += sc[j]; }
#pragma unroll
    for (int off = 32; off > 0; off >>= 1) sum += __shfl_xor(sum, off);
    const float inv = 1.0f / sum;
    bf16x8 o;
#pragma unroll
    for (int j = 0; j < 8; ++j) o[j] = (bf16_t)(sc[j] * inv);
    *(bf16x8*)&Aout[(size_t)row * FF + lane * 8] = o;
}

// --------------------------------------------------------------- NT bf16 GEMM
// C[M][N] = A[M][K] * B[N][K]^T, batched, bf16 out. 256x256 tile, BK=32,
// 8 waves (2M x 4N, wave tile 128x64), triple-buffered, prefetch distance 2,
// counted vmcnt(4) boundary (r2-proven). NEW: fine per-phase interleave —
// 4 phases x 8 MFMA per tile, ds_reads grouped ahead of use with counted
// lgkmcnt(2/4/0), stage issues spread 1 per phase (m196/m201 T3 lever).
__global__ __launch_bounds__(512, 2) void gemm_nt_pipe(
        const bf16_t* __restrict__ Abase, long long strideA, int lda,
        const bf16_t* __restrict__ Bbase, long long strideB, int ldb,
        bf16_t* __restrict__ Cbase, long long strideC, int ldc,
        int NT, const float* __restrict__ bias_m) {
    __shared__ __align__(16) bf16_t As[3][256 * 32];   // 3 x 16 KiB
    __shared__ __align__(16) bf16_t Bs[3][256 * 32];   // 3 x 16 KiB (96 KiB)
    const int tid = threadIdx.x;
    const int w = tid >> 6, lane = tid & 63;
    const int m0 = blockIdx.x * 256, n0 = blockIdx.y * 256;
    const bf16_t* A = Abase + (size_t)blockIdx.z * (size_t)strideA;
    const bf16_t* B = Bbase + (size_t)blockIdx.z * (size_t)strideB;
    bf16_t* C = Cbase + (size_t)blockIdx.z * (size_t)strideC;

    const int wm = w >> 2, wn = w & 3;   // wave tile: rows wm*128.., cols wn*64..

    // ---- staging addresses (4 single-inst slices per tile: A-lo, A-hi, B-lo, B-hi)
    const int srow0 = w * 16 + (lane >> 2);
    const int srow1 = 128 + srow0;
    const int sc0 = (lane & 3) ^ ((srow0 >> 1) & 3);  // inverse-swizzled source chunk
    const int sc1 = (lane & 3) ^ ((srow1 >> 1) & 3);
    const bf16_t* gA0 = A + (size_t)(m0 + srow0) * lda + sc0 * 8;
    const bf16_t* gA1 = A + (size_t)(m0 + srow1) * lda + sc1 * 8;
    const bf16_t* gB0 = B + (size_t)(n0 + srow0) * ldb + sc0 * 8;
    const bf16_t* gB1 = B + (size_t)(n0 + srow1) * ldb + sc1 * 8;
    const int ldsoff0 = (w * 16) * 32;        // wave-uniform LDS elem offsets
    const int ldsoff1 = (128 + w * 16) * 32;

#define ST1(gp, arr, bi, loff, kt)                                                  \
    __builtin_amdgcn_global_load_lds(                                               \
        (const __attribute__((address_space(1))) unsigned int*)((gp) + (kt) * 32),  \
        (__attribute__((address_space(3))) unsigned int*)&arr[bi][loff], 16, 0, 0)

    // ---- fragment-read offsets (swizzled on the read side, same XOR)
    const int kc = lane >> 4;                 // k-chunk 0..3 (8 bf16 each)
    int offA[8], offB[4];
#pragma unroll
    for (int mt = 0; mt < 8; ++mt) {
        const int r = wm * 128 + mt * 16 + (lane & 15);
        offA[mt] = r * 32 + ((kc ^ ((r >> 1) & 3)) << 3);
    }
#pragma unroll
    for (int nt = 0; nt < 4; ++nt) {
        const int r = wn * 64 + nt * 16 + (lane & 15);
        offB[nt] = r * 32 + ((kc ^ ((r >> 1) & 3)) << 3);
    }

    f32x4 acc[8][4] = {};
    const int mask = NT - 1;                  // NT is a power of two (64 or 16)

    // prologue: stage tiles 0 and 1 fully
    ST1(gA0, As, 0, ldsoff0, 0); ST1(gA1, As, 0, ldsoff1, 0);
    ST1(gB0, Bs, 0, ldsoff0, 0); ST1(gB1, Bs, 0, ldsoff1, 0);
    ST1(gA0, As, 1, ldsoff0, 1); ST1(gA1, As, 1, ldsoff1, 1);
    ST1(gB0, Bs, 1, ldsoff0, 1); ST1(gB1, Bs, 1, ldsoff1, 1);
    asm volatile("s_waitcnt vmcnt(4)\n\ts_barrier" ::: "memory");  // tile0 landed

    int cur = 0;
    for (int t = 0; t < NT; ++t) {
        const int sb = (cur == 0) ? 2 : cur - 1;      // buffer for tile t+2
        const int kt = (t + 2) & mask;                 // dummy re-stage at tail
        const bf16_t* as = As[cur];
        const bf16_t* bs = Bs[cur];
        bf16x8 af[8], bfr[4];
        // --- G0: A lower-half frags (4) + B lower pair (2) = 6 ds_read_b128
        af[0] = *(const bf16x8*)&as[offA[0]];
        af[1] = *(const bf16x8*)&as[offA[1]];
        af[2] = *(const bf16x8*)&as[offA[2]];
        af[3] = *(const bf16x8*)&as[offA[3]];
        bfr[0] = *(const bf16x8*)&bs[offB[0]];
        bfr[1] = *(const bf16x8*)&bs[offB[1]];
        __builtin_amdgcn_sched_barrier(0);
        // --- G1: B upper pair (2)
        bfr[2] = *(const bf16x8*)&bs[offB[2]];
        bfr[3] = *(const bf16x8*)&bs[offB[3]];
        __builtin_amdgcn_sched_barrier(0);
        ST1(gA0, As, sb, ldsoff0, kt);                // stage slice 0
        // phase 0: needs G0 -> leave G1's 2 outstanding
        asm volatile("s_waitcnt lgkmcnt(2)" ::: "memory");
        __builtin_amdgcn_sched_barrier(0);
        __builtin_amdgcn_s_setprio(1);
#pragma unroll
        for (int mt = 0; mt < 4; ++mt)
#pragma unroll
            for (int nt = 0; nt < 2; ++nt)
                acc[mt][nt] = __builtin_amdgcn_mfma_f32_16x16x32_bf16(
                    af[mt], bfr[nt], acc[mt][nt], 0, 0, 0);
        __builtin_amdgcn_s_setprio(0);
        __builtin_amdgcn_sched_barrier(0);
        // --- G2: A upper-half frags (4)
        af[4] = *(const bf16x8*)&as[offA[4]];
        af[5] = *(const bf16x8*)&as[offA[5]];
        af[6] = *(const bf16x8*)&as[offA[6]];
        af[7] = *(const bf16x8*)&as[offA[7]];
        __builtin_amdgcn_sched_barrier(0);
        ST1(gA1, As, sb, ldsoff1, kt);                // stage slice 1
        // phase 1: needs G1 -> leave G2's 4 outstanding
        asm volatile("s_waitcnt lgkmcnt(4)" ::: "memory");
        __builtin_amdgcn_sched_barrier(0);
        __builtin_amdgcn_s_setprio(1);
#pragma unroll
        for (int mt = 0; mt < 4; ++mt)
#pragma unroll
            for (int nt = 2; nt < 4; ++nt)
                acc[mt][nt] = __builtin_amdgcn_mfma_f32_16x16x32_bf16(
                    af[mt], bfr[nt], acc[mt][nt], 0, 0, 0);
        __builtin_amdgcn_s_setprio(0);
        __builtin_amdgcn_sched_barrier(0);
        ST1(gB0, Bs, sb, ldsoff0, kt);                // stage slice 2
        // phase 2: needs G2
        asm volatile("s_waitcnt lgkmcnt(0)" ::: "memory");
        __builtin_amdgcn_sched_barrier(0);
        __builtin_amdgcn_s_setprio(1);
#pragma unroll
        for (int mt = 4; mt < 8; ++mt)
#pragma unroll
            for (int nt = 0; nt < 2; ++nt)
                acc[mt][nt] = __builtin_amdgcn_mfma_f32_16x16x32_bf16(
                    af[mt], bfr[nt], acc[mt][nt], 0, 0, 0);
        __builtin_amdgcn_s_setprio(0);
        __builtin_amdgcn_sched_barrier(0);
        ST1(gB1, Bs, sb, ldsoff1, kt);                // stage slice 3
        // phase 3: no new data
        __builtin_amdgcn_s_setprio(1);
#pragma unroll
        for (int mt = 4; mt < 8; ++mt)
#pragma unroll
            for (int nt = 2; nt < 4; ++nt)
                acc[mt][nt] = __builtin_amdgcn_mfma_f32_16x16x32_bf16(
                    af[mt], bfr[nt], acc[mt][nt], 0, 0, 0);
        __builtin_amdgcn_s_setprio(0);
        __builtin_amdgcn_sched_barrier(0);
        // boundary: tile t+1 forced landed (per-wave, + barrier joins all waves);
        // tile t+2's 4 stages stay in flight
        asm volatile("s_waitcnt vmcnt(4)\n\ts_barrier" ::: "memory");
        cur = (cur == 2) ? 0 : cur + 1;
    }
#undef ST1

    // Epilogue: C/D layout row=(lane>>4)*4+reg, col=lane&15 (verified)
#pragma unroll
    for (int mt = 0; mt < 8; ++mt) {
#pragma unroll
        for (int r = 0; r < 4; ++r) {
            const int row = m0 + wm * 128 + mt * 16 + ((lane >> 4) << 2) + r;
            const float bm = bias_m ? bias_m[row] : 0.0f;
#pragma unroll
            for (int nt = 0; nt < 4; ++nt) {
                const int col = n0 + wn * 64 + nt * 16 + (lane & 15);
                C[(size_t)row * ldc + col] = (bf16_t)(acc[mt][nt][r] + bm);
            }
        }
    }
}

// -------------------------------------------------------------- final epilogue
// out[b][s][f] = x_norm(exact fp32) + alpha*Ot[b][s][f] + (1+beta)*Vt[b][s][f]
__global__ __launch_bounds__(256) void epilogue_kernel(const float* __restrict__ x,
                                                       const float* __restrict__ lw,
                                                       const float* __restrict__ lb,
                                                       const bf16_t* __restrict__ Ot,
                                                       const bf16_t* __restrict__ Vt,
                                                       const float* __restrict__ musig,
                                                       const float* __restrict__ alphap,
                                                       const float* __restrict__ betap,
                                                       float* __restrict__ out) {
    const size_t i4 = ((size_t)blockIdx.x * 256 + threadIdx.x) * 4;
    const size_t b = i4 >> 20;
    const size_t rr = i4 & 1048575;
    const float mu = musig[b], rs = musig[16 + b];
    const float alpha = alphap[0];
    const float onepb = 1.0f + betap[0];
    const float4 xv  = *(const float4*)&x[i4];
    const float4 wv  = *(const float4*)&lw[rr];
    const float4 bbv = *(const float4*)&lb[rr];
    const bf16x4 ov = *(const bf16x4*)&Ot[i4];
    const bf16x4 vv = *(const bf16x4*)&Vt[i4];
    float4 o;
    o.x = (xv.x - mu) * rs * wv.x + bbv.x + alpha * (float)ov[0] + onepb * (float)vv[0];
    o.y = (xv.y - mu) * rs * wv.y + bbv.y + alpha * (float)ov[1] + onepb * (float)vv[1];
    o.z = (xv.z - mu) * rs * wv.z + bbv.z + alpha * (float)ov[2] + onepb * (float)vv[2];
    o.w = (xv.w - mu) * rs * wv.w + bbv.w + alpha * (float)ov[3] + onepb * (float)vv[3];
    *(float4*)&out[i4] = o;
}

extern "C" void kernel_launch(void* const* d_in, const int* in_sizes, int n_in,
                              void* d_out, int out_size, void* d_ws, size_t ws_size,
                              hipStream_t stream) {
    const float* x   = (const float*)d_in[0];
    const float* Wq  = (const float*)d_in[1];
    const float* bq  = (const float*)d_in[2];
    const float* Wk  = (const float*)d_in[3];
    const float* bk  = (const float*)d_in[4];
    const float* Wv  = (const float*)d_in[5];
    const float* bv  = (const float*)d_in[6];
    const float* lw  = (const float*)d_in[7];
    const float* lb  = (const float*)d_in[8];
    const float* alp = (const float*)d_in[9];
    const float* bet = (const float*)d_in[10];
    float* out = (float*)d_out;

    char* ws = (char*)d_ws;
    float*  sums  = (float*)(ws + 0);           // 32 f32: sum[16], sumsq[16]
    float*  musig = (float*)(ws + 128);         // 32 f32: mu[16], rsig[16]
    float*  Qo    = (float*)(ws + 256);         // 16*512*4 f32 = 128 KiB
    float*  Ko    = (float*)(ws + 256 + 131072);
    bf16_t* Wvb   = (bf16_t*)(ws + 262400);     // 2048*2048 bf16 = 8 MiB
    bf16_t* Asm   = (bf16_t*)(ws + 8651008);    // 16*512*512 bf16 = 8 MiB
    bf16_t* Vt    = (bf16_t*)(ws + 17039616);   // 16*2048*512 bf16 = 32 MiB
    bf16_t* Y     = (bf16_t*)(ws + 50594048);   // 16*512*2048 bf16 = 32 MiB
    bf16_t* Ot    = Y;  // alias: Y is dead after gemm1 (gemm2 reads Vt+Asm only)

    zero_stats<<<1, 64, 0, stream>>>(sums);
    stats_kernel<<<dim3(64, 16), 256, 0, stream>>>(x, sums);
    finalize_stats<<<1, 64, 0, stream>>>(sums, musig);
    cast_wv<<<4096, 256, 0, stream>>>(Wv, Wvb);
    ynorm_kernel<<<dim3(16, 64, 16), 256, 0, stream>>>(x, lw, lb, musig, Y);
    qk_kernel<<<2048, 256, 0, stream>>>(Y, Wq, bq, Wk, bk, Qo, Ko);
    softmax_kernel<<<2048, 256, 0, stream>>>(Qo, Ko, Asm);
    // Vt[b,t,f] = sum_s Wv[t,s]*Y[b,f,s] + bv[t]   (M=2048,N=512,K=2048, NT=64)
    gemm_nt_pipe<<<dim3(8, 2, 16), 512, 0, stream>>>(
        Wvb, 0, SS, Y, 1 << 20, SS, Vt, 1 << 20, FF, 64, bv);
    // Ot[b,t,f] = sum_g Vt[b,t,g]*Asm[b,f,g]       (M=2048,N=512,K=512, NT=16)
    gemm_nt_pipe<<<dim3(8, 2, 16), 512, 0, stream>>>(
        Vt, 1 << 20, FF, Asm, FF * FF, FF, Ot, 1 << 20, FF, 16, nullptr);
    epilogue_kernel<<<16384, 256, 0, stream>>>(x, lw, lb, Ot, Vt, musig, alp, bet, out);
}

// Round 5
// 213.407 us; speedup vs baseline: 1.1105x; 1.0395x over previous
//
#include <hip/hip_runtime.h>
#include <hip/hip_bf16.h>

// Problem constants
#define NB 16        // batches
#define SS 2048      // S
#define FF 512       // F

typedef __bf16 bf16_t;
typedef __bf16 bf16x8 __attribute__((ext_vector_type(8)));
typedef __bf16 bf16x4 __attribute__((ext_vector_type(4)));
typedef float  f32x4  __attribute__((ext_vector_type(4)));

// ---------------------------------------------------------------- LN stats
__global__ __launch_bounds__(64) void zero_stats(float* sums) {
    if (threadIdx.x < 32) sums[threadIdx.x] = 0.0f;
}

__global__ __launch_bounds__(256) void stats_kernel(const float* __restrict__ x,
                                                    float* __restrict__ sums) {
    const int b = blockIdx.y;
    const float* xb = x + ((size_t)b << 20) + (size_t)blockIdx.x * 16384;
    float s = 0.0f, ss = 0.0f;
#pragma unroll
    for (int i = 0; i < 16; ++i) {
        const float4 v = *(const float4*)&xb[(threadIdx.x + i * 256) * 4];
        s  += v.x + v.y + v.z + v.w;
        ss += v.x * v.x + v.y * v.y + v.z * v.z + v.w * v.w;
    }
#pragma unroll
    for (int off = 32; off > 0; off >>= 1) {
        s  += __shfl_down(s, off);
        ss += __shfl_down(ss, off);
    }
    __shared__ float ps[4], pss[4];
    const int w = threadIdx.x >> 6, lane = threadIdx.x & 63;
    if (lane == 0) { ps[w] = s; pss[w] = ss; }
    __syncthreads();
    if (threadIdx.x == 0) {
        atomicAdd(&sums[b],      ps[0] + ps[1] + ps[2] + ps[3]);
        atomicAdd(&sums[16 + b], pss[0] + pss[1] + pss[2] + pss[3]);
    }
}

__global__ __launch_bounds__(64) void finalize_stats(const float* __restrict__ sums,
                                                     float* __restrict__ musig) {
    const int b = threadIdx.x;
    if (b < 16) {
        const float inv_n = 1.0f / 1048576.0f;
        const float mu  = sums[b] * inv_n;
        const float var = sums[16 + b] * inv_n - mu * mu;
        musig[b]      = mu;
        musig[16 + b] = rsqrtf(var + 1e-5f);
    }
}

// ------------------------------------------------- x_norm -> Y bf16 [b][f][s]
__global__ __launch_bounds__(256) void ynorm_kernel(const float* __restrict__ x,
                                                    const float* __restrict__ lw,
                                                    const float* __restrict__ lb,
                                                    const float* __restrict__ musig,
                                                    bf16_t* __restrict__ Y) {
    __shared__ bf16_t t[32][33];
    const int b = blockIdx.z;
    const int f0 = blockIdx.x * 32, s0 = blockIdx.y * 32;
    const float mu = musig[b], rs = musig[16 + b];
    const int c = threadIdx.x & 31, rb = threadIdx.x >> 5;   // rb in 0..7
#pragma unroll
    for (int i = 0; i < 4; ++i) {
        const int s_loc = rb + i * 8;
        const size_t idx = (size_t)(s0 + s_loc) * FF + f0 + c;
        const float yv = (x[((size_t)b << 20) + idx] - mu) * rs * lw[idx] + lb[idx];
        t[s_loc][c] = (bf16_t)yv;
    }
    __syncthreads();
#pragma unroll
    for (int i = 0; i < 4; ++i) {
        const int f_loc = rb + i * 8;
        Y[((size_t)b << 20) + (size_t)(f0 + f_loc) * SS + s0 + c] = t[c][f_loc];
    }
}

// ---------------------------------------------------------------- Wv -> bf16
__global__ __launch_bounds__(256) void cast_wv(const float* __restrict__ Wv,
                                               bf16_t* __restrict__ Wvb) {
    const size_t i = ((size_t)blockIdx.x * 256 + threadIdx.x) * 4;
    const float4 v = *(const float4*)&Wv[i];
    bf16x4 o;
    o[0] = (bf16_t)v.x; o[1] = (bf16_t)v.y; o[2] = (bf16_t)v.z; o[3] = (bf16_t)v.w;
    *(bf16x4*)&Wvb[i] = o;
}

// -------------------------------------------------- Q,K: [b*F] rows, R=4 each
__global__ __launch_bounds__(256) void qk_kernel(const bf16_t* __restrict__ Y,
                                                 const float* __restrict__ Wq,
                                                 const float* __restrict__ bq,
                                                 const float* __restrict__ Wk,
                                                 const float* __restrict__ bk,
                                                 float* __restrict__ Qo,
                                                 float* __restrict__ Ko) {
    const int w = threadIdx.x >> 6, lane = threadIdx.x & 63;
    const int row = blockIdx.x * 4 + w;              // b*512 + f
    const bf16_t* y = Y + (size_t)row * SS;
    float qa[4] = {0.f, 0.f, 0.f, 0.f}, ka[4] = {0.f, 0.f, 0.f, 0.f};
#pragma unroll
    for (int c = 0; c < 4; ++c) {
        const int s = c * 512 + lane * 8;
        const bf16x8 yv = *(const bf16x8*)&y[s];
        float yf[8];
#pragma unroll
        for (int j = 0; j < 8; ++j) yf[j] = (float)yv[j];
#pragma unroll
        for (int r = 0; r < 4; ++r) {
            const float4 a0 = *(const float4*)&Wq[r * SS + s];
            const float4 a1 = *(const float4*)&Wq[r * SS + s + 4];
            const float4 c0 = *(const float4*)&Wk[r * SS + s];
            const float4 c1 = *(const float4*)&Wk[r * SS + s + 4];
            qa[r] += yf[0]*a0.x + yf[1]*a0.y + yf[2]*a0.z + yf[3]*a0.w
                   + yf[4]*a1.x + yf[5]*a1.y + yf[6]*a1.z + yf[7]*a1.w;
            ka[r] += yf[0]*c0.x + yf[1]*c0.y + yf[2]*c0.z + yf[3]*c0.w
                   + yf[4]*c1.x + yf[5]*c1.y + yf[6]*c1.z + yf[7]*c1.w;
        }
    }
#pragma unroll
    for (int off = 32; off > 0; off >>= 1) {
#pragma unroll
        for (int r = 0; r < 4; ++r) {
            qa[r] += __shfl_down(qa[r], off);
            ka[r] += __shfl_down(ka[r], off);
        }
    }
    if (lane == 0) {
#pragma unroll
        for (int r = 0; r < 4; ++r) {
            Qo[(size_t)row * 4 + r] = qa[r] + bq[r];
            Ko[(size_t)row * 4 + r] = ka[r] + bk[r];
        }
    }
}

// ----------------------------------- A = softmax(Q K^T / sqrt(4)), bf16 output
__global__ __launch_bounds__(256) void softmax_kernel(const float* __restrict__ Qo,
                                                      const float* __restrict__ Ko,
                                                      bf16_t* __restrict__ Aout) {
    const int w = threadIdx.x >> 6, lane = threadIdx.x & 63;
    const int row = blockIdx.x * 4 + w;              // b*512 + f
    const int b = row >> 9;
    const float4 q = *(const float4*)&Qo[(size_t)row * 4];
    const float* kb = Ko + (size_t)b * FF * 4;
    float sc[8];
#pragma unroll
    for (int j = 0; j < 8; ++j) {
        const float4 kv = *(const float4*)&kb[(lane * 8 + j) * 4];
        sc[j] = (q.x*kv.x + q.y*kv.y + q.z*kv.z + q.w*kv.w) * 0.5f;
    }
    float mx = sc[0];
#pragma unroll
    for (int j = 1; j < 8; ++j) mx = fmaxf(mx, sc[j]);
#pragma unroll
    for (int off = 32; off > 0; off >>= 1) mx = fmaxf(mx, __shfl_xor(mx, off));
    float sum = 0.f;
#pragma unroll
    for (int j = 0; j < 8; ++j) { sc[j] = __expf(sc[j] - mx); sum += sc[j]; }
#pragma unroll
    for (int off = 32; off > 0; off >>= 1) sum += __shfl_xor(sum, off);
    const float inv = 1.0f / sum;
    bf16x8 o;
#pragma unroll
    for (int j = 0; j < 8; ++j) o[j] = (bf16_t)(sc[j] * inv);
    *(bf16x8*)&Aout[(size_t)row * FF + lane * 8] = o;
}

// --------------------------------------------------------------- NT bf16 GEMM
// C[M][N] = A[M][K] * B[N][K]^T, batched, bf16 out. 256x256 tile, BK=64,
// 8 waves (2M x 4N, wave tile 128x64), 512 threads, 128 KiB LDS (2 buffers x
// [2 k-half][256 rows][32 k]). m201-style schedule derived hazard-free:
// per K-tile 4 phases (kk, m-half) of 16 MFMA; one half-matrix stage (2
// global_load_lds) per phase; vmcnt(4)+s_barrier before P1 and P3 only —
// the 4 allowed-outstanding loads always target the OTHER buffer or the
// not-yet-read k-half, so no drain-to-0 in the loop (T3+T4).
__global__ __launch_bounds__(512, 2) void gemm_nt_8phase(
        const bf16_t* __restrict__ Abase, long long strideA, int lda,
        const bf16_t* __restrict__ Bbase, long long strideB, int ldb,
        bf16_t* __restrict__ Cbase, long long strideC, int ldc,
        int NTILES, const float* __restrict__ bias_m) {
    __shared__ __align__(16) bf16_t As[2][16384];   // [buf][kk*8192 + row*32 + swz]
    __shared__ __align__(16) bf16_t Bs[2][16384];   // total 128 KiB
    const int tid = threadIdx.x;
    const int w = tid >> 6, lane = tid & 63;
    const int m0 = blockIdx.x * 256, n0 = blockIdx.y * 256;
    const bf16_t* A = Abase + (size_t)blockIdx.z * (size_t)strideA;
    const bf16_t* B = Bbase + (size_t)blockIdx.z * (size_t)strideB;
    bf16_t* C = Cbase + (size_t)blockIdx.z * (size_t)strideC;
    const int wm = w >> 2, wn = w & 3;   // wave tile rows wm*128.., cols wn*64..

    // ---- staging: per half-matrix = 16 KiB = 2 insts/wave, 1 KiB each.
    // inst (w,j) covers rows (w*2+j)*16..+15 (32 bf16 = 64 B per row in the
    // k-half region). lane L: row += L>>2, 16B slot L&3. Source pre-swizzled:
    // data (row r, chunk c in half) sits at slot (c ^ ((r>>1)&3)).
    const int rr0 = (w * 2 + 0) * 16 + (lane >> 2);
    const int rr1 = (w * 2 + 1) * 16 + (lane >> 2);
    const int sw0 = ((lane & 3) ^ ((rr0 >> 1) & 3)) * 8;
    const int sw1 = ((lane & 3) ^ ((rr1 >> 1) & 3)) * 8;
    const bf16_t* gA0 = A + (size_t)(m0 + rr0) * lda + sw0;
    const bf16_t* gA1 = A + (size_t)(m0 + rr1) * lda + sw1;
    const bf16_t* gB0 = B + (size_t)(n0 + rr0) * ldb + sw0;
    const bf16_t* gB1 = B + (size_t)(n0 + rr1) * ldb + sw1;
    const int d0 = (w * 2 + 0) * 512;   // wave-uniform LDS elem offset in half-region
    const int d1 = (w * 2 + 1) * 512;

#define STA(bi, h, ko) do {                                                          \
    __builtin_amdgcn_global_load_lds(                                                \
        (const __attribute__((address_space(1))) unsigned int*)(gA0 + (ko) + (h)*32),\
        (__attribute__((address_space(3))) unsigned int*)&As[bi][(h)*8192 + d0], 16, 0, 0); \
    __builtin_amdgcn_global_load_lds(                                                \
        (const __attribute__((address_space(1))) unsigned int*)(gA1 + (ko) + (h)*32),\
        (__attribute__((address_space(3))) unsigned int*)&As[bi][(h)*8192 + d1], 16, 0, 0); \
} while (0)
#define STB(bi, h, ko) do {                                                          \
    __builtin_amdgcn_global_load_lds(                                                \
        (const __attribute__((address_space(1))) unsigned int*)(gB0 + (ko) + (h)*32),\
        (__attribute__((address_space(3))) unsigned int*)&Bs[bi][(h)*8192 + d0], 16, 0, 0); \
    __builtin_amdgcn_global_load_lds(                                                \
        (const __attribute__((address_space(1))) unsigned int*)(gB1 + (ko) + (h)*32),\
        (__attribute__((address_space(3))) unsigned int*)&Bs[bi][(h)*8192 + d1], 16, 0, 0); \
} while (0)

    // ---- fragment ds_read offsets (same XOR on the read side; 2-way max)
    const int cs = lane >> 4;           // chunk-within-half 0..3
    int offA[2][8], offB[2][4];
#pragma unroll
    for (int kk = 0; kk < 2; ++kk) {
#pragma unroll
        for (int mt = 0; mt < 8; ++mt) {
            const int r = wm * 128 + mt * 16 + (lane & 15);
            offA[kk][mt] = kk * 8192 + r * 32 + ((cs ^ ((r >> 1) & 3)) << 3);
        }
#pragma unroll
        for (int nt = 0; nt < 4; ++nt) {
            const int r = wn * 64 + nt * 16 + (lane & 15);
            offB[kk][nt] = kk * 8192 + r * 32 + ((cs ^ ((r >> 1) & 3)) << 3);
        }
    }

#define DS_A(kk, mh) do { _Pragma("unroll")                                   \
    for (int i = 0; i < 4; ++i) af[i] = *(const bf16x8*)&as[offA[kk][(mh)*4 + i]]; } while (0)
#define DS_B(kk) do { _Pragma("unroll")                                       \
    for (int i = 0; i < 4; ++i) bfr[i] = *(const bf16x8*)&bs[offB[kk][i]]; } while (0)
#define MFMA16(mh) do { _Pragma("unroll")                                     \
    for (int i = 0; i < 4; ++i) { _Pragma("unroll")                           \
        for (int nt = 0; nt < 4; ++nt)                                        \
            acc[(mh)*4 + i][nt] = __builtin_amdgcn_mfma_f32_16x16x32_bf16(    \
                af[i], bfr[nt], acc[(mh)*4 + i][nt], 0, 0, 0); } } while (0)
#define WAITB asm volatile("s_waitcnt vmcnt(4)\n\ts_barrier" ::: "memory")
#define LGKM0 do { asm volatile("s_waitcnt lgkmcnt(0)" ::: "memory");         \
                   __builtin_amdgcn_sched_barrier(0); } while (0)
#define SBAR  __builtin_amdgcn_sched_barrier(0)

    f32x4 acc[8][4] = {};
    const int mask = NTILES - 1;        // power of two

    // prologue: tile 0 into buf 0 (order: A-h0, B-h0, A-h1, B-h1)
    STA(0, 0, 0); STB(0, 0, 0); STA(0, 1, 0); STB(0, 1, 0);

    for (int t = 0; t < NTILES; ++t) {
        const int cur = t & 1, oth = cur ^ 1;
        const int ko = ((t + 1) & mask) * 64;   // next tile k-offset (dummy at tail)
        const bf16_t* as = As[cur];
        const bf16_t* bs = Bs[cur];
        bf16x8 af[4], bfr[4];
        WAITB;                                   // A-h0,B-h0 of tile t landed
        // P1 (kk0, m-lo)
        DS_A(0, 0); DS_B(0); SBAR; STA(oth, 0, ko); LGKM0;
        __builtin_amdgcn_s_setprio(1); MFMA16(0); __builtin_amdgcn_s_setprio(0); SBAR;
        // P2 (kk0, m-hi) — B kk0 frags reused
        DS_A(0, 1); SBAR; STB(oth, 0, ko); LGKM0;
        __builtin_amdgcn_s_setprio(1); MFMA16(1); __builtin_amdgcn_s_setprio(0); SBAR;
        WAITB;                                   // A-h1,B-h1 of tile t landed
        // P3 (kk1, m-lo)
        DS_A(1, 0); DS_B(1); SBAR; STA(oth, 1, ko); LGKM0;
        __builtin_amdgcn_s_setprio(1); MFMA16(0); __builtin_amdgcn_s_setprio(0); SBAR;
        // P4 (kk1, m-hi)
        DS_A(1, 1); SBAR; STB(oth, 1, ko); LGKM0;
        __builtin_amdgcn_s_setprio(1); MFMA16(1); __builtin_amdgcn_s_setprio(0); SBAR;
    }
#undef STA
#undef STB
#undef DS_A
#undef DS_B
#undef MFMA16
#undef WAITB
#undef LGKM0
#undef SBAR

    // Epilogue: C/D layout row=(lane>>4)*4+reg, col=lane&15 (verified)
#pragma unroll
    for (int mt = 0; mt < 8; ++mt) {
#pragma unroll
        for (int r = 0; r < 4; ++r) {
            const int row = m0 + wm * 128 + mt * 16 + ((lane >> 4) << 2) + r;
            const float bm = bias_m ? bias_m[row] : 0.0f;
#pragma unroll
            for (int nt = 0; nt < 4; ++nt) {
                const int col = n0 + wn * 64 + nt * 16 + (lane & 15);
                C[(size_t)row * ldc + col] = (bf16_t)(acc[mt][nt][r] + bm);
            }
        }
    }
}

// -------------------------------------------------------------- final epilogue
// out[b][s][f] = x_norm(exact fp32) + alpha*Ot[b][s][f] + (1+beta)*Vt[b][s][f]
__global__ __launch_bounds__(256) void epilogue_kernel(const float* __restrict__ x,
                                                       const float* __restrict__ lw,
                                                       const float* __restrict__ lb,
                                                       const bf16_t* __restrict__ Ot,
                                                       const bf16_t* __restrict__ Vt,
                                                       const float* __restrict__ musig,
                                                       const float* __restrict__ alphap,
                                                       const float* __restrict__ betap,
                                                       float* __restrict__ out) {
    const size_t i4 = ((size_t)blockIdx.x * 256 + threadIdx.x) * 4;
    const size_t b = i4 >> 20;
    const size_t rr = i4 & 1048575;
    const float mu = musig[b], rs = musig[16 + b];
    const float alpha = alphap[0];
    const float onepb = 1.0f + betap[0];
    const float4 xv  = *(const float4*)&x[i4];
    const float4 wv  = *(const float4*)&lw[rr];
    const float4 bbv = *(const float4*)&lb[rr];
    const bf16x4 ov = *(const bf16x4*)&Ot[i4];
    const bf16x4 vv = *(const bf16x4*)&Vt[i4];
    float4 o;
    o.x = (xv.x - mu) * rs * wv.x + bbv.x + alpha * (float)ov[0] + onepb * (float)vv[0];
    o.y = (xv.y - mu) * rs * wv.y + bbv.y + alpha * (float)ov[1] + onepb * (float)vv[1];
    o.z = (xv.z - mu) * rs * wv.z + bbv.z + alpha * (float)ov[2] + onepb * (float)vv[2];
    o.w = (xv.w - mu) * rs * wv.w + bbv.w + alpha * (float)ov[3] + onepb * (float)vv[3];
    *(float4*)&out[i4] = o;
}

extern "C" void kernel_launch(void* const* d_in, const int* in_sizes, int n_in,
                              void* d_out, int out_size, void* d_ws, size_t ws_size,
                              hipStream_t stream) {
    const float* x   = (const float*)d_in[0];
    const float* Wq  = (const float*)d_in[1];
    const float* bq  = (const float*)d_in[2];
    const float* Wk  = (const float*)d_in[3];
    const float* bk  = (const float*)d_in[4];
    const float* Wv  = (const float*)d_in[5];
    const float* bv  = (const float*)d_in[6];
    const float* lw  = (const float*)d_in[7];
    const float* lb  = (const float*)d_in[8];
    const float* alp = (const float*)d_in[9];
    const float* bet = (const float*)d_in[10];
    float* out = (float*)d_out;

    char* ws = (char*)d_ws;
    float*  sums  = (float*)(ws + 0);           // 32 f32: sum[16], sumsq[16]
    float*  musig = (float*)(ws + 128);         // 32 f32: mu[16], rsig[16]
    float*  Qo    = (float*)(ws + 256);         // 16*512*4 f32 = 128 KiB
    float*  Ko    = (float*)(ws + 256 + 131072);
    bf16_t* Wvb   = (bf16_t*)(ws + 262400);     // 2048*2048 bf16 = 8 MiB
    bf16_t* Asm   = (bf16_t*)(ws + 8651008);    // 16*512*512 bf16 = 8 MiB
    bf16_t* Vt    = (bf16_t*)(ws + 17039616);   // 16*2048*512 bf16 = 32 MiB
    bf16_t* Y     = (bf16_t*)(ws + 50594048);   // 16*512*2048 bf16 = 32 MiB
    bf16_t* Ot    = Y;  // alias: Y is dead after gemm1 (gemm2 reads Vt+Asm only)

    zero_stats<<<1, 64, 0, stream>>>(sums);
    stats_kernel<<<dim3(64, 16), 256, 0, stream>>>(x, sums);
    finalize_stats<<<1, 64, 0, stream>>>(sums, musig);
    cast_wv<<<4096, 256, 0, stream>>>(Wv, Wvb);
    ynorm_kernel<<<dim3(16, 64, 16), 256, 0, stream>>>(x, lw, lb, musig, Y);
    qk_kernel<<<2048, 256, 0, stream>>>(Y, Wq, bq, Wk, bk, Qo, Ko);
    softmax_kernel<<<2048, 256, 0, stream>>>(Qo, Ko, Asm);
    // Vt[b,t,f] = sum_s Wv[t,s]*Y[b,f,s] + bv[t]   (M=2048,N=512,K=2048 -> 32 tiles)
    gemm_nt_8phase<<<dim3(8, 2, 16), 512, 0, stream>>>(
        Wvb, 0, SS, Y, 1 << 20, SS, Vt, 1 << 20, FF, 32, bv);
    // Ot[b,t,f] = sum_g Vt[b,t,g]*Asm[b,f,g]       (M=2048,N=512,K=512 -> 8 tiles)
    gemm_nt_8phase<<<dim3(8, 2, 16), 512, 0, stream>>>(
        Vt, 1 << 20, FF, Asm, FF * FF, FF, Ot, 1 << 20, FF, 8, nullptr);
    epilogue_kernel<<<16384, 256, 0, stream>>>(x, lw, lb, Ot, Vt, musig, alp, bet, out);
}

// Round 6
// 195.111 us; speedup vs baseline: 1.2147x; 1.0938x over previous
//
#include <hip/hip_runtime.h>
#include <hip/hip_bf16.h>

// Problem constants
#define NB 16        // batches
#define SS 2048      // S
#define FF 512       // F

typedef __bf16 bf16_t;
typedef __bf16 bf16x8 __attribute__((ext_vector_type(8)));
typedef __bf16 bf16x4 __attribute__((ext_vector_type(4)));
typedef float  f32x4  __attribute__((ext_vector_type(4)));

// ---------------------------------------------------------------- LN stats
// per-block partial sums (no atomics): partials[0][b][blk], partials[1][b][blk]
__global__ __launch_bounds__(256) void stats_kernel(const float* __restrict__ x,
                                                    float* __restrict__ partials) {
    const int b = blockIdx.y;
    const float* xb = x + ((size_t)b << 20) + (size_t)blockIdx.x * 16384;
    float s = 0.0f, ss = 0.0f;
#pragma unroll
    for (int i = 0; i < 16; ++i) {
        const float4 v = *(const float4*)&xb[(threadIdx.x + i * 256) * 4];
        s  += v.x + v.y + v.z + v.w;
        ss += v.x * v.x + v.y * v.y + v.z * v.z + v.w * v.w;
    }
#pragma unroll
    for (int off = 32; off > 0; off >>= 1) {
        s  += __shfl_down(s, off);
        ss += __shfl_down(ss, off);
    }
    __shared__ float ps[4], pss[4];
    const int w = threadIdx.x >> 6, lane = threadIdx.x & 63;
    if (lane == 0) { ps[w] = s; pss[w] = ss; }
    __syncthreads();
    if (threadIdx.x == 0) {
        partials[b * 64 + blockIdx.x]        = ps[0] + ps[1] + ps[2] + ps[3];
        partials[1024 + b * 64 + blockIdx.x] = pss[0] + pss[1] + pss[2] + pss[3];
    }
}

__global__ __launch_bounds__(256) void finalize_stats(const float* __restrict__ partials,
                                                      float* __restrict__ musig) {
    const int tid = threadIdx.x;          // 0..255
    const int b = tid >> 4, i = tid & 15;
    float s = 0.f, ss = 0.f;
#pragma unroll
    for (int j = 0; j < 4; ++j) {
        s  += partials[b * 64 + i * 4 + j];
        ss += partials[1024 + b * 64 + i * 4 + j];
    }
#pragma unroll
    for (int off = 8; off > 0; off >>= 1) {
        s  += __shfl_xor(s, off);
        ss += __shfl_xor(ss, off);
    }
    if (i == 0) {
        const float inv_n = 1.0f / 1048576.0f;
        const float mu  = s * inv_n;
        const float var = ss * inv_n - mu * mu;
        musig[b]      = mu;
        musig[16 + b] = rsqrtf(var + 1e-5f);
    }
}

// ------------------------------------------------- x_norm -> Y bf16 [b][f][s]
__global__ __launch_bounds__(256) void ynorm_kernel(const float* __restrict__ x,
                                                    const float* __restrict__ lw,
                                                    const float* __restrict__ lb,
                                                    const float* __restrict__ musig,
                                                    bf16_t* __restrict__ Y) {
    __shared__ bf16_t t[32][33];
    const int b = blockIdx.z;
    const int f0 = blockIdx.x * 32, s0 = blockIdx.y * 32;
    const float mu = musig[b], rs = musig[16 + b];
    const int c = threadIdx.x & 31, rb = threadIdx.x >> 5;   // rb in 0..7
#pragma unroll
    for (int i = 0; i < 4; ++i) {
        const int s_loc = rb + i * 8;
        const size_t idx = (size_t)(s0 + s_loc) * FF + f0 + c;
        const float yv = (x[((size_t)b << 20) + idx] - mu) * rs * lw[idx] + lb[idx];
        t[s_loc][c] = (bf16_t)yv;
    }
    __syncthreads();
#pragma unroll
    for (int i = 0; i < 4; ++i) {
        const int f_loc = rb + i * 8;
        Y[((size_t)b << 20) + (size_t)(f0 + f_loc) * SS + s0 + c] = t[c][f_loc];
    }
}

// ---------------------------------------------------------------- Wv -> bf16
__global__ __launch_bounds__(256) void cast_wv(const float* __restrict__ Wv,
                                               bf16_t* __restrict__ Wvb) {
    const size_t i = ((size_t)blockIdx.x * 256 + threadIdx.x) * 4;
    const float4 v = *(const float4*)&Wv[i];
    bf16x4 o;
    o[0] = (bf16_t)v.x; o[1] = (bf16_t)v.y; o[2] = (bf16_t)v.z; o[3] = (bf16_t)v.w;
    *(bf16x4*)&Wvb[i] = o;
}

// -------------------------------------------------- Q,K: [b*F] rows, R=4 each
__global__ __launch_bounds__(256) void qk_kernel(const bf16_t* __restrict__ Y,
                                                 const float* __restrict__ Wq,
                                                 const float* __restrict__ bq,
                                                 const float* __restrict__ Wk,
                                                 const float* __restrict__ bk,
                                                 float* __restrict__ Qo,
                                                 float* __restrict__ Ko) {
    const int w = threadIdx.x >> 6, lane = threadIdx.x & 63;
    const int row = blockIdx.x * 4 + w;              // b*512 + f
    const bf16_t* y = Y + (size_t)row * SS;
    float qa[4] = {0.f, 0.f, 0.f, 0.f}, ka[4] = {0.f, 0.f, 0.f, 0.f};
#pragma unroll
    for (int c = 0; c < 4; ++c) {
        const int s = c * 512 + lane * 8;
        const bf16x8 yv = *(const bf16x8*)&y[s];
        float yf[8];
#pragma unroll
        for (int j = 0; j < 8; ++j) yf[j] = (float)yv[j];
#pragma unroll
        for (int r = 0; r < 4; ++r) {
            const float4 a0 = *(const float4*)&Wq[r * SS + s];
            const float4 a1 = *(const float4*)&Wq[r * SS + s + 4];
            const float4 c0 = *(const float4*)&Wk[r * SS + s];
            const float4 c1 = *(const float4*)&Wk[r * SS + s + 4];
            qa[r] += yf[0]*a0.x + yf[1]*a0.y + yf[2]*a0.z + yf[3]*a0.w
                   + yf[4]*a1.x + yf[5]*a1.y + yf[6]*a1.z + yf[7]*a1.w;
            ka[r] += yf[0]*c0.x + yf[1]*c0.y + yf[2]*c0.z + yf[3]*c0.w
                   + yf[4]*c1.x + yf[5]*c1.y + yf[6]*c1.z + yf[7]*c1.w;
        }
    }
#pragma unroll
    for (int off = 32; off > 0; off >>= 1) {
#pragma unroll
        for (int r = 0; r < 4; ++r) {
            qa[r] += __shfl_down(qa[r], off);
            ka[r] += __shfl_down(ka[r], off);
        }
    }
    if (lane == 0) {
#pragma unroll
        for (int r = 0; r < 4; ++r) {
            Qo[(size_t)row * 4 + r] = qa[r] + bq[r];
            Ko[(size_t)row * 4 + r] = ka[r] + bk[r];
        }
    }
}

// ----------------------------------- A = softmax(Q K^T / sqrt(4)), bf16 output
__global__ __launch_bounds__(256) void softmax_kernel(const float* __restrict__ Qo,
                                                      const float* __restrict__ Ko,
                                                      bf16_t* __restrict__ Aout) {
    const int w = threadIdx.x >> 6, lane = threadIdx.x & 63;
    const int row = blockIdx.x * 4 + w;              // b*512 + f
    const int b = row >> 9;
    const float4 q = *(const float4*)&Qo[(size_t)row * 4];
    const float* kb = Ko + (size_t)b * FF * 4;
    float sc[8];
#pragma unroll
    for (int j = 0; j < 8; ++j) {
        const float4 kv = *(const float4*)&kb[(lane * 8 + j) * 4];
        sc[j] = (q.x*kv.x + q.y*kv.y + q.z*kv.z + q.w*kv.w) * 0.5f;
    }
    float mx = sc[0];
#pragma unroll
    for (int j = 1; j < 8; ++j) mx = fmaxf(mx, sc[j]);
#pragma unroll
    for (int off = 32; off > 0; off >>= 1) mx = fmaxf(mx, __shfl_xor(mx, off));
    float sum = 0.f;
#pragma unroll
    for (int j = 0; j < 8; ++j) { sc[j] = __expf(sc[j] - mx); sum += sc[j]; }
#pragma unroll
    for (int off = 32; off > 0; off >>= 1) sum += __shfl_xor(sum, off);
    const float inv = 1.0f / sum;
    bf16x8 o;
#pragma unroll
    for (int j = 0; j < 8; ++j) o[j] = (bf16_t)(sc[j] * inv);
    *(bf16x8*)&Aout[(size_t)row * FF + lane * 8] = o;
}

// --------------------------------------------------------------- NT bf16 GEMM
// C[M][N] = A[M][K] * B[N][K]^T, batched, bf16 out. 256x256 tile, BK=64,
// 8 waves (2M x 4N, wave tile 128x64), 512 threads, 128 KiB LDS, 2-buffer
// ping-pong. m201-exact phase skeleton: per phase {ds_reads; stage;
// [vmcnt(4) one phase AHEAD of the reader]; s_barrier; lgkmcnt(0);
// setprio(1); 16 MFMA; setprio(0); s_barrier}. vmcnt(4) only at P2/P4:
// at each wait the 4 oldest outstanding loads are exactly the half-tile the
// NEXT phase reads; the barrier makes per-wave counts block-global.
// Grid is 1D (256 blocks) with XCD-bijective swizzle: each XCD's 32 blocks
// cover 2 batches (L2 locality) instead of all 16.
__global__ __launch_bounds__(512, 2) void gemm_nt_8phase(
        const bf16_t* __restrict__ Abase, long long strideA, int lda,
        const bf16_t* __restrict__ Bbase, long long strideB, int ldb,
        bf16_t* __restrict__ Cbase, long long strideC, int ldc,
        int NTILES, const float* __restrict__ bias_m) {
    __shared__ __align__(16) bf16_t As[2][16384];   // [buf][kk*8192 + row*32 + swz]
    __shared__ __align__(16) bf16_t Bs[2][16384];   // total 128 KiB
    const int tid = threadIdx.x;
    const int w = tid >> 6, lane = tid & 63;

    // XCD-bijective swizzle (nwg = 256, 256 % 8 == 0)
    const int nchunk = gridDim.x >> 3;                               // 32
    const int wgid = (blockIdx.x & 7) * nchunk + (blockIdx.x >> 3);
    const int bz = wgid >> 4;            // batch
    const int rem = wgid & 15;
    const int m0 = (rem & 7) * 256, n0 = (rem >> 3) * 256;

    const bf16_t* A = Abase + (size_t)bz * (size_t)strideA;
    const bf16_t* B = Bbase + (size_t)bz * (size_t)strideB;
    bf16_t* C = Cbase + (size_t)bz * (size_t)strideC;
    const int wm = w >> 2, wn = w & 3;   // wave tile rows wm*128.., cols wn*64..

    // ---- staging: per half-matrix = 16 KiB = 2 insts/wave, 1 KiB each.
    const int rr0 = (w * 2 + 0) * 16 + (lane >> 2);
    const int rr1 = (w * 2 + 1) * 16 + (lane >> 2);
    const int sw0 = ((lane & 3) ^ ((rr0 >> 1) & 3)) * 8;
    const int sw1 = ((lane & 3) ^ ((rr1 >> 1) & 3)) * 8;
    const bf16_t* gA0 = A + (size_t)(m0 + rr0) * lda + sw0;
    const bf16_t* gA1 = A + (size_t)(m0 + rr1) * lda + sw1;
    const bf16_t* gB0 = B + (size_t)(n0 + rr0) * ldb + sw0;
    const bf16_t* gB1 = B + (size_t)(n0 + rr1) * ldb + sw1;
    const int d0 = (w * 2 + 0) * 512;   // wave-uniform LDS elem offset in half-region
    const int d1 = (w * 2 + 1) * 512;

#define STA(bi, h, ko) do {                                                          \
    __builtin_amdgcn_global_load_lds(                                                \
        (const __attribute__((address_space(1))) unsigned int*)(gA0 + (ko) + (h)*32),\
        (__attribute__((address_space(3))) unsigned int*)&As[bi][(h)*8192 + d0], 16, 0, 0); \
    __builtin_amdgcn_global_load_lds(                                                \
        (const __attribute__((address_space(1))) unsigned int*)(gA1 + (ko) + (h)*32),\
        (__attribute__((address_space(3))) unsigned int*)&As[bi][(h)*8192 + d1], 16, 0, 0); \
} while (0)
#define STB(bi, h, ko) do {                                                          \
    __builtin_amdgcn_global_load_lds(                                                \
        (const __attribute__((address_space(1))) unsigned int*)(gB0 + (ko) + (h)*32),\
        (__attribute__((address_space(3))) unsigned int*)&Bs[bi][(h)*8192 + d0], 16, 0, 0); \
    __builtin_amdgcn_global_load_lds(                                                \
        (const __attribute__((address_space(1))) unsigned int*)(gB1 + (ko) + (h)*32),\
        (__attribute__((address_space(3))) unsigned int*)&Bs[bi][(h)*8192 + d1], 16, 0, 0); \
} while (0)

    // ---- fragment ds_read offsets (same XOR on the read side; conflict-free)
    const int cs = lane >> 4;           // chunk-within-half 0..3
    int offA[2][8], offB[2][4];
#pragma unroll
    for (int kk = 0; kk < 2; ++kk) {
#pragma unroll
        for (int mt = 0; mt < 8; ++mt) {
            const int r = wm * 128 + mt * 16 + (lane & 15);
            offA[kk][mt] = kk * 8192 + r * 32 + ((cs ^ ((r >> 1) & 3)) << 3);
        }
#pragma unroll
        for (int nt = 0; nt < 4; ++nt) {
            const int r = wn * 64 + nt * 16 + (lane & 15);
            offB[kk][nt] = kk * 8192 + r * 32 + ((cs ^ ((r >> 1) & 3)) << 3);
        }
    }

#define DS_A(kk, mh) do { _Pragma("unroll")                                   \
    for (int i = 0; i < 4; ++i) af[i] = *(const bf16x8*)&as[offA[kk][(mh)*4 + i]]; } while (0)
#define DS_B(kk) do { _Pragma("unroll")                                       \
    for (int i = 0; i < 4; ++i) bfr[i] = *(const bf16x8*)&bs[offB[kk][i]]; } while (0)
#define MFMA16(mh) do { _Pragma("unroll")                                     \
    for (int i = 0; i < 4; ++i) { _Pragma("unroll")                           \
        for (int nt = 0; nt < 4; ++nt)                                        \
            acc[(mh)*4 + i][nt] = __builtin_amdgcn_mfma_f32_16x16x32_bf16(    \
                af[i], bfr[nt], acc[(mh)*4 + i][nt], 0, 0, 0); } } while (0)
#define VM4   asm volatile("s_waitcnt vmcnt(4)" ::: "memory")
#define HBAR  __builtin_amdgcn_s_barrier()
#define LGKM0 do { asm volatile("s_waitcnt lgkmcnt(0)" ::: "memory");         \
                   __builtin_amdgcn_sched_barrier(0); } while (0)
#define SBAR  __builtin_amdgcn_sched_barrier(0)
#define PRIO1 __builtin_amdgcn_s_setprio(1)
#define PRIO0 __builtin_amdgcn_s_setprio(0)

    f32x4 acc[8][4] = {};
    const int mask = NTILES - 1;        // power of two

    // prologue: tile 0 into buf 0; force first half-tile landed
    STA(0, 0, 0); STB(0, 0, 0); STA(0, 1, 0); STB(0, 1, 0);
    VM4; HBAR;

    for (int t = 0; t < NTILES; ++t) {
        const int oth = (t & 1) ^ 1;
        const int ko = ((t + 1) & mask) * 64;   // next tile k-offset (dummy at tail)
        const bf16_t* as = As[t & 1];
        const bf16_t* bs = Bs[t & 1];
        bf16x8 af[4], bfr[4];
        // ---- P1 (kk0, m-lo): A-h0/B-h0 landed via prev P4's vmcnt+barrier
        DS_A(0, 0); DS_B(0); SBAR;
        STA(oth, 0, ko); SBAR;
        HBAR;
        LGKM0;
        PRIO1; MFMA16(0); PRIO0; SBAR;
        HBAR;
        // ---- P2 (kk0, m-hi): B kk0 frags reused
        DS_A(0, 1); SBAR;
        STB(oth, 0, ko); SBAR;
        VM4;                      // forces A-h1,B-h1 of tile t landed (P3 reads)
        HBAR;
        LGKM0;
        PRIO1; MFMA16(1); PRIO0; SBAR;
        HBAR;
        // ---- P3 (kk1, m-lo)
        DS_A(1, 0); DS_B(1); SBAR;
        STA(oth, 1, ko); SBAR;
        HBAR;
        LGKM0;
        PRIO1; MFMA16(0); PRIO0; SBAR;
        HBAR;
        // ---- P4 (kk1, m-hi)
        DS_A(1, 1); SBAR;
        STB(oth, 1, ko); SBAR;
        VM4;                      // forces A-h0,B-h0 of tile t+1 landed (next P1)
        HBAR;
        LGKM0;
        PRIO1; MFMA16(1); PRIO0; SBAR;
        HBAR;
    }
#undef STA
#undef STB
#undef DS_A
#undef DS_B
#undef MFMA16
#undef VM4
#undef HBAR
#undef LGKM0
#undef SBAR
#undef PRIO1
#undef PRIO0

    // Epilogue: C/D layout row=(lane>>4)*4+reg, col=lane&15 (verified)
#pragma unroll
    for (int mt = 0; mt < 8; ++mt) {
#pragma unroll
        for (int r = 0; r < 4; ++r) {
            const int row = m0 + wm * 128 + mt * 16 + ((lane >> 4) << 2) + r;
            const float bm = bias_m ? bias_m[row] : 0.0f;
#pragma unroll
            for (int nt = 0; nt < 4; ++nt) {
                const int col = n0 + wn * 64 + nt * 16 + (lane & 15);
                C[(size_t)row * ldc + col] = (bf16_t)(acc[mt][nt][r] + bm);
            }
        }
    }
}

// -------------------------------------------------------------- final epilogue
// out[b][s][f] = x_norm(exact fp32) + alpha*Ot[b][s][f] + (1+beta)*Vt[b][s][f]
__global__ __launch_bounds__(256) void epilogue_kernel(const float* __restrict__ x,
                                                       const float* __restrict__ lw,
                                                       const float* __restrict__ lb,
                                                       const bf16_t* __restrict__ Ot,
                                                       const bf16_t* __restrict__ Vt,
                                                       const float* __restrict__ musig,
                                                       const float* __restrict__ alphap,
                                                       const float* __restrict__ betap,
                                                       float* __restrict__ out) {
    const size_t i4 = ((size_t)blockIdx.x * 256 + threadIdx.x) * 4;
    const size_t b = i4 >> 20;
    const size_t rr = i4 & 1048575;
    const float mu = musig[b], rs = musig[16 + b];
    const float alpha = alphap[0];
    const float onepb = 1.0f + betap[0];
    const float4 xv  = *(const float4*)&x[i4];
    const float4 wv  = *(const float4*)&lw[rr];
    const float4 bbv = *(const float4*)&lb[rr];
    const bf16x4 ov = *(const bf16x4*)&Ot[i4];
    const bf16x4 vv = *(const bf16x4*)&Vt[i4];
    float4 o;
    o.x = (xv.x - mu) * rs * wv.x + bbv.x + alpha * (float)ov[0] + onepb * (float)vv[0];
    o.y = (xv.y - mu) * rs * wv.y + bbv.y + alpha * (float)ov[1] + onepb * (float)vv[1];
    o.z = (xv.z - mu) * rs * wv.z + bbv.z + alpha * (float)ov[2] + onepb * (float)vv[2];
    o.w = (xv.w - mu) * rs * wv.w + bbv.w + alpha * (float)ov[3] + onepb * (float)vv[3];
    *(float4*)&out[i4] = o;
}

extern "C" void kernel_launch(void* const* d_in, const int* in_sizes, int n_in,
                              void* d_out, int out_size, void* d_ws, size_t ws_size,
                              hipStream_t stream) {
    const float* x   = (const float*)d_in[0];
    const float* Wq  = (const float*)d_in[1];
    const float* bq  = (const float*)d_in[2];
    const float* Wk  = (const float*)d_in[3];
    const float* bk  = (const float*)d_in[4];
    const float* Wv  = (const float*)d_in[5];
    const float* bv  = (const float*)d_in[6];
    const float* lw  = (const float*)d_in[7];
    const float* lb  = (const float*)d_in[8];
    const float* alp = (const float*)d_in[9];
    const float* bet = (const float*)d_in[10];
    float* out = (float*)d_out;

    char* ws = (char*)d_ws;
    float*  musig = (float*)(ws + 128);         // 32 f32: mu[16], rsig[16]
    float*  Qo    = (float*)(ws + 256);         // 16*512*4 f32 = 128 KiB
    float*  Ko    = (float*)(ws + 256 + 131072);
    bf16_t* Wvb   = (bf16_t*)(ws + 262400);     // 2048*2048 bf16 = 8 MiB
    bf16_t* Asm   = (bf16_t*)(ws + 8651008);    // 16*512*512 bf16 = 8 MiB
    float*  partials = (float*)(ws + 8651008);  // 2048 f32 (8 KiB) — dead before Asm is written
    bf16_t* Vt    = (bf16_t*)(ws + 17039616);   // 16*2048*512 bf16 = 32 MiB
    bf16_t* Y     = (bf16_t*)(ws + 50594048);   // 16*512*2048 bf16 = 32 MiB
    bf16_t* Ot    = Y;  // alias: Y is dead after gemm1 (gemm2 reads Vt+Asm only)

    stats_kernel<<<dim3(64, 16), 256, 0, stream>>>(x, partials);
    finalize_stats<<<1, 256, 0, stream>>>(partials, musig);
    cast_wv<<<4096, 256, 0, stream>>>(Wv, Wvb);
    ynorm_kernel<<<dim3(16, 64, 16), 256, 0, stream>>>(x, lw, lb, musig, Y);
    qk_kernel<<<2048, 256, 0, stream>>>(Y, Wq, bq, Wk, bk, Qo, Ko);
    softmax_kernel<<<2048, 256, 0, stream>>>(Qo, Ko, Asm);
    // Vt[b,t,f] = sum_s Wv[t,s]*Y[b,f,s] + bv[t]   (M=2048,N=512,K=2048 -> 32 tiles)
    gemm_nt_8phase<<<256, 512, 0, stream>>>(
        Wvb, 0, SS, Y, 1 << 20, SS, Vt, 1 << 20, FF, 32, bv);
    // Ot[b,t,f] = sum_g Vt[b,t,g]*Asm[b,f,g]       (M=2048,N=512,K=512 -> 8 tiles)
    gemm_nt_8phase<<<256, 512, 0, stream>>>(
        Vt, 1 << 20, FF, Asm, FF * FF, FF, Ot, 1 << 20, FF, 8, nullptr);
    epilogue_kernel<<<16384, 256, 0, stream>>>(x, lw, lb, Ot, Vt, musig, alp, bet, out);
}